// Round 13
// baseline (1321.432 us; speedup 1.0000x reference)
//
#include <hip/hip_runtime.h>
#include <hip/hip_bf16.h>
#include <stdint.h>

// ============================================================================
// MultiHeadAttention: y = softmax((xq Wq^T)(xk Wk^T)^T * scale) (xv Wv^T) Wo^T
// B=2, S=2048, H=32, D=128, DM=4096. I/O float32.
// R13: R12's register-pipelined gemm256 with the REAL register budget —
// __launch_bounds__(512,1) instead of (512,2). The (512,2) bound capped the
// allocator at 128 VGPR while the pipeline needs ~244 -> total spill (R12's
// 602us, VALUBusy 7.8%). LDS=128KB already limits residency to 1 block/CU,
// so min-waves=1 costs zero occupancy. Attn (R9) and cvt unchanged.
// ============================================================================

using u16 = unsigned short;
using u32 = unsigned int;

typedef __attribute__((ext_vector_type(8))) short bf16x8;  // MFMA A/B frag (8 bf16)
typedef __attribute__((ext_vector_type(8))) u16 u16x8;
typedef __attribute__((ext_vector_type(4))) u16 u16x4;
typedef __attribute__((ext_vector_type(4))) float f32x4;   // MFMA C/D frag

#define MFMA_BF16(A, B, C) __builtin_amdgcn_mfma_f32_16x16x32_bf16((A), (B), (C), 0, 0, 0)

static constexpr int kS = 2048, kDM = 4096, kD = 128;
static constexpr size_t kMat = (size_t)4096 * 4096;
// SCALE * log2(e): softmax computed in exp2 domain
static constexpr float kScaleLog2e = 0.08838834764831845f * 1.44269504088896340736f;

static __device__ __forceinline__ void gload_lds16(const u16* g, u16* l) {
  __builtin_amdgcn_global_load_lds((const __attribute__((address_space(1))) void*)g,
                                   (__attribute__((address_space(3))) void*)l, 16, 0, 0);
}

static __device__ __forceinline__ u16 f2bf(float f) {  // RNE f32 -> bf16 bits (sw)
  u32 u = __float_as_uint(f);
  u32 r = u + 0x7FFFu + ((u >> 16) & 1u);
  return (u16)(r >> 16);
}

static __device__ __forceinline__ float bf2f(u16 x) {  // exact bf16 -> f32
  return __uint_as_float((u32)x << 16);
}

static __device__ __forceinline__ u16 nbf(float f) {  // native cast (hw cvt)
  union { __hip_bfloat16 h; u16 u; } cv;
  cv.h = __float2bfloat16(f);
  return cv.u;
}

static __device__ __forceinline__ u16x8 cvt8(float4 a, float4 b) {
  u16x8 r;
  r[0] = f2bf(a.x); r[1] = f2bf(a.y); r[2] = f2bf(a.z); r[3] = f2bf(a.w);
  r[4] = f2bf(b.x); r[5] = f2bf(b.y); r[6] = f2bf(b.z); r[7] = f2bf(b.w);
  return r;
}

// ---------------------------------------------------------------------------
// f32 -> bf16 bulk conversion: 7 matrices of kMat elems. Grid (X, 7).
// ---------------------------------------------------------------------------
__global__ __launch_bounds__(256) void cvt_kernel(
    const float* __restrict__ s0, const float* __restrict__ s1,
    const float* __restrict__ s2, const float* __restrict__ s3,
    const float* __restrict__ s4, const float* __restrict__ s5,
    const float* __restrict__ s6, u16* __restrict__ dst) {
  const int y = blockIdx.y;
  const float* s = (y == 0) ? s0 : (y == 1) ? s1 : (y == 2) ? s2 : (y == 3) ? s3
                  : (y == 4) ? s4 : (y == 5) ? s5 : s6;
  u16* d = dst + (size_t)y * kMat;
  const size_t nchunk = kMat / 8;
  const size_t step = (size_t)gridDim.x * 256;
  for (size_t c = (size_t)blockIdx.x * 256 + threadIdx.x; c < nchunk; c += step) {
    const float* p = s + c * 8;
    float4 a = *(const float4*)p;
    float4 b = *(const float4*)(p + 4);
    *(u16x8*)(d + c * 8) = cvt8(a, b);
  }
}

// ---------------------------------------------------------------------------
// 256x256 8-phase GEMM, register-pipelined (R12 structure). Per phase:
// {ds_reads for NEXT cluster; stage; barrier; MFMA on previous-phase frags;
// barrier}. p3: vmcnt(4) then prefetch B(t+1)+A01(t+1).
// ---------------------------------------------------------------------------
template <bool TRANS, bool OUT_F32>
static __device__ __forceinline__ void gemm256(const u16* __restrict__ X,
                                               const u16* __restrict__ W,
                                               void* __restrict__ Yv,
                                               u16* __restrict__ lds,
                                               int m0, int n0) {
  constexpr int NT = kDM / 64;
  const int tid = threadIdx.x;
  const int lane = tid & 63;
  const int w = tid >> 6;
  const int fr = lane & 15;
  const int fq = lane >> 4;
  const int wr = w >> 2;  // 0..1  (M half)
  const int wc = w & 3;   // 0..3  (N quarter)

  const int srow = tid >> 3;
  const int scol = ((tid & 7) ^ (srow & 7)) * 8;
  const u16* Xrow = X + (size_t)(m0 + srow) * kDM + scol;
  const u16* Wrow = W + (size_t)(n0 + srow) * kDM + scol;
  const int w512 = w * 512;

  const int rBb = wc * 64 + fr;
  const int rAb = wr * 128 + fr;
  const int swz = fr & 7;

  f32x4 acc[8][4] = {};
  bf16x8 bfrA[4][2], bfrB[4][2];  // B frags, alternate per K-tile
  bf16x8 afA[2][2], afB[2][2];    // A frags, alternate per phase

#define STAGE2(ROWP, qrow, k0, ldq)                                        \
  do {                                                                     \
    gload_lds16((ROWP) + (size_t)(qrow) * kDM + (k0), &lds[(ldq) + w512]); \
    gload_lds16((ROWP) + (size_t)((qrow) + 64) * kDM + (k0),               \
                &lds[(ldq) + 4096 + w512]);                                \
  } while (0)

#define RD_B(BOFF, nf, ks) \
  (*(const bf16x8*)&lds[(BOFF) + (rBb + (nf) * 16) * 64 + ((((ks) * 4 + fq) ^ swz) * 8)])
#define RD_A(AOFF, mi, ks) \
  (*(const bf16x8*)&lds[(AOFF) + (rAb + (mi) * 16) * 64 + ((((ks) * 4 + fq) ^ swz) * 8)])

#define CLUSTER(mia, BARR, AARR)                                                \
  do {                                                                          \
    __builtin_amdgcn_s_setprio(1);                                              \
    _Pragma("unroll") for (int mj = 0; mj < 2; ++mj)                            \
    _Pragma("unroll") for (int nf = 0; nf < 4; ++nf)                            \
    _Pragma("unroll") for (int ks = 0; ks < 2; ++ks)                            \
      acc[(mia) + mj][nf] =                                                     \
          TRANS ? MFMA_BF16(BARR[nf][ks], AARR[mj][ks], acc[(mia) + mj][nf])    \
                : MFMA_BF16(AARR[mj][ks], BARR[nf][ks], acc[(mia) + mj][nf]);   \
    __builtin_amdgcn_s_setprio(0);                                              \
  } while (0)

// K-tile with compile-time dbuf DC; BC = this tile's B frags (resident),
// BN = next tile's B frags (prefetched at p3). Entering invariant: BC and
// afA (= A[0,1] of tile t) are loaded. Stagger: p0->A1(t+1), p1->B0(t+2),
// p2->B1(t+2), p3->A0(t+2). vmcnt(4) at p3-start (drains tile t+1).
#define KTILE(DC, t, BC, BN)                                                   \
  {                                                                            \
    constexpr int Boff = (DC) * 32768;                                         \
    constexpr int Aoff = Boff + 16384;                                         \
    constexpr int BoffN = ((DC) ^ 1) * 32768;                                  \
    constexpr int AoffN = BoffN + 16384;                                       \
    /* p0: read afB=A[2,3]; stage A1(t+1); c0(BC, afA) */                      \
    _Pragma("unroll") for (int mj = 0; mj < 2; ++mj)                           \
    _Pragma("unroll") for (int ks = 0; ks < 2; ++ks)                           \
      afB[mj][ks] = RD_A(Aoff, 2 + mj, ks);                                    \
    if ((t) + 1 < NT) STAGE2(Xrow, 128, ((t) + 1) * 64, BoffN + 24576);        \
    __builtin_amdgcn_s_barrier();                                              \
    CLUSTER(0, BC, afA);                                                       \
    __builtin_amdgcn_s_barrier();                                              \
    /* p1: read afA=A[4,5]; stage B0(t+2); c2(BC, afB) */                      \
    _Pragma("unroll") for (int mj = 0; mj < 2; ++mj)                           \
    _Pragma("unroll") for (int ks = 0; ks < 2; ++ks)                           \
      afA[mj][ks] = RD_A(Aoff, 4 + mj, ks);                                    \
    if ((t) + 2 < NT) STAGE2(Wrow, 0, ((t) + 2) * 64, Boff + 0);               \
    __builtin_amdgcn_s_barrier();                                              \
    CLUSTER(2, BC, afB);                                                       \
    __builtin_amdgcn_s_barrier();                                              \
    /* p2: read afB=A[6,7]; stage B1(t+2); c4(BC, afA) */                      \
    _Pragma("unroll") for (int mj = 0; mj < 2; ++mj)                           \
    _Pragma("unroll") for (int ks = 0; ks < 2; ++ks)                           \
      afB[mj][ks] = RD_A(Aoff, 6 + mj, ks);                                    \
    if ((t) + 2 < NT) STAGE2(Wrow, 128, ((t) + 2) * 64, Boff + 8192);          \
    __builtin_amdgcn_s_barrier();                                              \
    CLUSTER(4, BC, afA);                                                       \
    __builtin_amdgcn_s_barrier();                                              \
    /* p3: vmcnt(4|0); prefetch BN=B(t+1), afA=A[0,1](t+1); stage A0(t+2);     \
       c6(BC, afB) */                                                          \
    if ((t) + 2 < NT)                                                          \
      asm volatile("s_waitcnt vmcnt(4)" ::: "memory");                         \
    else                                                                       \
      asm volatile("s_waitcnt vmcnt(0)" ::: "memory");                         \
    if ((t) + 1 < NT) {                                                        \
      _Pragma("unroll") for (int nf = 0; nf < 4; ++nf)                         \
      _Pragma("unroll") for (int ks = 0; ks < 2; ++ks)                         \
        BN[nf][ks] = RD_B(BoffN, nf, ks);                                      \
      _Pragma("unroll") for (int mj = 0; mj < 2; ++mj)                         \
      _Pragma("unroll") for (int ks = 0; ks < 2; ++ks)                         \
        afA[mj][ks] = RD_A(AoffN, mj, ks);                                     \
    }                                                                          \
    if ((t) + 2 < NT) STAGE2(Xrow, 0, ((t) + 2) * 64, Boff + 16384);           \
    __builtin_amdgcn_s_barrier();                                              \
    CLUSTER(6, BC, afB);                                                       \
    __builtin_amdgcn_s_barrier();                                              \
  }

  // prologue: t0 {B0,B1,A0,A1} dbuf0; t1 {B0,B1,A0} dbuf1.
  STAGE2(Wrow, 0, 0, 0);
  STAGE2(Wrow, 128, 0, 8192);
  STAGE2(Xrow, 0, 0, 16384);
  STAGE2(Xrow, 128, 0, 24576);
  STAGE2(Wrow, 0, 64, 32768);
  STAGE2(Wrow, 128, 64, 32768 + 8192);
  STAGE2(Xrow, 0, 64, 32768 + 16384);
  asm volatile("s_waitcnt vmcnt(6)" ::: "memory");  // tile0 fully landed
  __builtin_amdgcn_s_barrier();
  // initial frags: B(0) and A[0,1](0)
#pragma unroll
  for (int nf = 0; nf < 4; ++nf)
#pragma unroll
    for (int ks = 0; ks < 2; ++ks) bfrA[nf][ks] = RD_B(0, nf, ks);
#pragma unroll
  for (int mj = 0; mj < 2; ++mj)
#pragma unroll
    for (int ks = 0; ks < 2; ++ks) afA[mj][ks] = RD_A(16384, mj, ks);

  for (int tt = 0; tt < NT; tt += 2) {
    KTILE(0, tt, bfrA, bfrB);
    KTILE(1, tt + 1, bfrB, bfrA);
  }
#undef KTILE
#undef CLUSTER
#undef RD_A
#undef RD_B
#undef STAGE2

  // epilogue: C/D layout col=lane&15, row=(lane>>4)*4+i [m89/m91]
#pragma unroll
  for (int mi = 0; mi < 8; ++mi)
#pragma unroll
    for (int nf = 0; nf < 4; ++nf) {
      int row, col;
      if constexpr (TRANS) {
        row = n0 + wc * 64 + nf * 16 + fq * 4;
        col = m0 + wr * 128 + mi * 16 + fr;
      } else {
        row = m0 + wr * 128 + mi * 16 + fq * 4;
        col = n0 + wc * 64 + nf * 16 + fr;
      }
      if constexpr (OUT_F32) {
        float* yp = (float*)Yv + (size_t)row * kDM + col;
#pragma unroll
        for (int i = 0; i < 4; ++i) yp[(size_t)i * kDM] = acc[mi][nf][i];
      } else {
        u16* yp = (u16*)Yv + (size_t)row * kDM + col;
#pragma unroll
        for (int i = 0; i < 4; ++i) yp[(size_t)i * kDM] = f2bf(acc[mi][nf][i]);
      }
    }
}

// XCD-aware bijective remap (hw flat id -> work id; 8 XCDs, nwg%8==0)
static __device__ __forceinline__ int xcd_swz(int id, int cpx) {
  return (id & 7) * cpx + (id >> 3);
}

// NOTE: min-waves=1 — LDS (128KB) already limits to 1 block/CU; (512,2)
// would cap VGPR at 128 and spill the ~244-VGPR register pipeline (R12 bug).
__global__ __launch_bounds__(512, 1) void proj_qk256_kernel(const u16* __restrict__ wsb,
                                                            u16* __restrict__ qp,
                                                            u16* __restrict__ kp) {
  __shared__ u16 lds[65536];
  const int z = blockIdx.z;
  const int s = xcd_swz(blockIdx.y * 16 + blockIdx.x, 32);
  const int m0 = (s >> 4) * 256, n0 = (s & 15) * 256;
  gemm256<false, false>(wsb + (size_t)z * kMat, wsb + (size_t)(3 + z) * kMat,
                        z ? kp : qp, lds, m0, n0);
}

__global__ __launch_bounds__(512, 1) void proj_vT256_kernel(const u16* __restrict__ wsb,
                                                            u16* __restrict__ vpT) {
  __shared__ u16 lds[65536];
  const int s = xcd_swz(blockIdx.y * 16 + blockIdx.x, 32);
  gemm256<true, false>(wsb + 2 * kMat, wsb + 5 * kMat, vpT, lds,
                       (s >> 4) * 256, (s & 15) * 256);
}

__global__ __launch_bounds__(512, 1) void out_proj256_kernel(const u16* __restrict__ ctx,
                                                             const u16* __restrict__ Wob,
                                                             float* __restrict__ out) {
  __shared__ u16 lds[65536];
  const int s = xcd_swz(blockIdx.y * 16 + blockIdx.x, 32);
  gemm256<false, true>(ctx, Wob, out, lds, (s >> 4) * 256, (s & 15) * 256);
}

// ---------------------------------------------------------------------------
// FALLBACK path (ws too small): in-GEMM convert staging (R5-verified).
// ---------------------------------------------------------------------------
template <bool A_BF16, bool TRANS, bool OUT_F32>
static __device__ __forceinline__ void gemm_conv(const void* Xv, const float* Wf,
                                                 void* Yv, u16* __restrict__ Als,
                                                 u16* __restrict__ Bls) {
  constexpr int KD = 4096;
  const int tid = threadIdx.x;
  const int lane = tid & 63;
  const int w = tid >> 6;
  const int fr = lane & 15;
  const int fq = lane >> 4;
  const int m0 = blockIdx.y * 128;
  const int n0 = blockIdx.x * 128;

  const int r0 = tid >> 2, cc0 = (tid & 3) * 8;
  const int r1 = r0 + 64;
  const int sr = lane >> 2, sc = (lane & 3) * 8;
  const int u0 = w * 2, u1 = w * 2 + 1;

  const u16* Xb = (const u16*)Xv;
  const float* Xf = (const float*)Xv;

  const int wm = (w >> 1) * 64;
  const int wn = (w & 1) * 64;

  f32x4 acc[4][4] = {};

  for (int kt = 0; kt < KD / 32; ++kt) {
    const int ko = kt * 32;
    if constexpr (A_BF16) {
      gload_lds16(Xb + (size_t)(m0 + u0 * 16 + sr) * KD + ko + sc, &Als[u0 * 512]);
      gload_lds16(Xb + (size_t)(m0 + u1 * 16 + sr) * KD + ko + sc, &Als[u1 * 512]);
    } else {
      const float* p0 = Xf + (size_t)(m0 + r0) * KD + ko + cc0;
      const float* p1 = Xf + (size_t)(m0 + r1) * KD + ko + cc0;
      float4 a0 = *(const float4*)(p0);
      float4 a1 = *(const float4*)(p0 + 4);
      float4 a2 = *(const float4*)(p1);
      float4 a3 = *(const float4*)(p1 + 4);
      *(u16x8*)&Als[r0 * 32 + cc0] = cvt8(a0, a1);
      *(u16x8*)&Als[r1 * 32 + cc0] = cvt8(a2, a3);
    }
    {
      const float* p0 = Wf + (size_t)(n0 + r0) * KD + ko + cc0;
      const float* p1 = Wf + (size_t)(n0 + r1) * KD + ko + cc0;
      float4 b0 = *(const float4*)(p0);
      float4 b1 = *(const float4*)(p0 + 4);
      float4 b2 = *(const float4*)(p1);
      float4 b3 = *(const float4*)(p1 + 4);
      *(u16x8*)&Bls[r0 * 32 + cc0] = cvt8(b0, b1);
      *(u16x8*)&Bls[r1 * 32 + cc0] = cvt8(b2, b3);
    }
    __syncthreads();

    bf16x8 af[4], bfv[4];
#pragma unroll
    for (int i = 0; i < 4; ++i)
      af[i] = *(const bf16x8*)&Als[(wm + i * 16 + fr) * 32 + fq * 8];
#pragma unroll
    for (int i = 0; i < 4; ++i)
      bfv[i] = *(const bf16x8*)&Bls[(wn + i * 16 + fr) * 32 + fq * 8];
#pragma unroll
    for (int a = 0; a < 4; ++a)
#pragma unroll
      for (int bb = 0; bb < 4; ++bb) {
        if constexpr (TRANS)
          acc[a][bb] = MFMA_BF16(bfv[a], af[bb], acc[a][bb]);
        else
          acc[a][bb] = MFMA_BF16(af[a], bfv[bb], acc[a][bb]);
      }
    __syncthreads();
  }

#pragma unroll
  for (int a = 0; a < 4; ++a)
#pragma unroll
    for (int bb = 0; bb < 4; ++bb) {
      const int row = TRANS ? (n0 + wn + a * 16 + fq * 4) : (m0 + wm + a * 16 + fq * 4);
      const int col = TRANS ? (m0 + wm + bb * 16 + fr) : (n0 + wn + bb * 16 + fr);
      if constexpr (OUT_F32) {
        float* yp = (float*)Yv + (size_t)row * kDM + col;
#pragma unroll
        for (int i = 0; i < 4; ++i) yp[(size_t)i * kDM] = acc[a][bb][i];
      } else {
        u16* yp = (u16*)Yv + (size_t)row * kDM + col;
#pragma unroll
        for (int i = 0; i < 4; ++i) yp[(size_t)i * kDM] = f2bf(acc[a][bb][i]);
      }
    }
}

__global__ __launch_bounds__(256) void proj_qk_conv_kernel(
    const float* __restrict__ q, const float* __restrict__ k,
    const float* __restrict__ Wq, const float* __restrict__ Wk,
    u16* __restrict__ qp, u16* __restrict__ kp) {
  __shared__ u16 Als[128 * 32];
  __shared__ u16 Bls[128 * 32];
  const int z = blockIdx.z;
  gemm_conv<false, false, false>(z ? k : q, z ? Wk : Wq, z ? kp : qp, Als, Bls);
}

__global__ __launch_bounds__(256) void proj_vT_conv_kernel(
    const float* __restrict__ v, const float* __restrict__ Wv, u16* __restrict__ vpT) {
  __shared__ u16 Als[128 * 32];
  __shared__ u16 Bls[128 * 32];
  gemm_conv<false, true, false>(v, Wv, vpT, Als, Bls);
}

__global__ __launch_bounds__(256) void out_proj_conv_kernel(const u16* __restrict__ ctx,
                                                            const float* __restrict__ Wo,
                                                            float* __restrict__ out) {
  __shared__ u16 Als[128 * 32];
  __shared__ u16 Bls[128 * 32];
  gemm_conv<true, false, true>(ctx, Wo, out, Als, Bls);
}

// ---------------------------------------------------------------------------
// Flash attention (R9, unchanged): grid (8,64) block 512 = 8 waves.
// Swapped QK^T; conflict-free b64 P-stores; ones-V denom; defer-max;
// reg-staged async K/V prefetch; XCD swizzle.
// ---------------------------------------------------------------------------
__global__ __launch_bounds__(512) void attn_kernel(const u16* __restrict__ qp,
                                                   const u16* __restrict__ kp,
                                                   const u16* __restrict__ vpT,
                                                   u16* __restrict__ ctx) {
  constexpr int KB = 64;
  constexpr int NT = kS / KB;   // 32 tiles
  constexpr int PST = 72;       // P row stride (elems, 16B-aligned rows)
  constexpr float THR = 11.5f;  // defer-max threshold (log2 units ~ e^8)

  __shared__ u16 Kls[KB * 128];        // 16 KB [key][d] chunk-swizzled
  __shared__ u16 Vt[kD * KB];          // 16 KB [d][key] chunk-swizzled
  __shared__ u16 Pls[8][2 * 16 * PST]; // 36 KB per-wave P tiles [q][key]

  const int tid = threadIdx.x, lane = tid & 63, w = tid >> 6;  // w: 0..7
  const int fr = lane & 15, fq = lane >> 4;

  const int wg = blockIdx.y * 8 + blockIdx.x;
  const int o = (wg & 7) * 64 + (wg >> 3);
  const int bh = o >> 3;
  const int b = bh >> 5, h = bh & 31;
  const int q0 = (o & 7) * 256;

  const u16* qbase = qp + ((size_t)b * kS) * kDM + h * kD;
  const u16* kbase = kp + ((size_t)b * kS) * kDM + h * kD;
  const u16* vtbase = vpT + (size_t)(h * kD) * kDM + b * kS;  // row d, stride kDM

  bf16x8 qf[2][4];
#pragma unroll
  for (int rb = 0; rb < 2; ++rb)
#pragma unroll
    for (int kc = 0; kc < 4; ++kc) {
      const u16x8 raw = *(const u16x8*)(qbase +
          (size_t)(q0 + w * 32 + rb * 16 + fr) * kDM + kc * 32 + fq * 8);
      bf16x8 s;
#pragma unroll
      for (int j = 0; j < 8; ++j) s[j] = (short)f2bf(bf2f(raw[j]) * kScaleLog2e);
      qf[rb][kc] = s;
    }

  f32x4 oacc[2][9] = {};
  float mrun[2] = {-1e30f, -1e30f};

  bf16x8 ones;
#pragma unroll
  for (int j = 0; j < 8; ++j) ones[j] = (short)0x3F80;  // bf16 1.0

  const int krl = lane >> 4, kdp = lane & 15;
  const int vdl = lane >> 3, vc = lane & 7;
  const int rk0 = (w * 2 + 0) * 4 + krl;
  const int rk1 = (w * 2 + 1) * 4 + krl;
  const int dv0 = (w * 2 + 0) * 8 + vdl;
  const int dv1 = (w * 2 + 1) * 8 + vdl;
  const u16* kg0 = kbase + (size_t)rk0 * kDM + kdp * 8;
  const u16* kg1 = kbase + (size_t)rk1 * kDM + kdp * 8;
  const u16* vg0 = vtbase + (size_t)dv0 * kDM + vc * 8;
  const u16* vg1 = vtbase + (size_t)dv1 * kDM + vc * 8;
  u16* kl0 = &Kls[rk0 * 128 + ((kdp ^ (rk0 & 7)) * 8)];
  u16* kl1 = &Kls[rk1 * 128 + ((kdp ^ (rk1 & 7)) * 8)];
  u16* vl0 = &Vt[dv0 * KB + ((vc ^ (dv0 & 7)) * 8)];
  u16* vl1 = &Vt[dv1 * KB + ((vc ^ (dv1 & 7)) * 8)];

  u16x8 kr0v, kr1v, vr0v, vr1v;
  kr0v = *(const u16x8*)kg0;
  kr1v = *(const u16x8*)kg1;
  vr0v = *(const u16x8*)vg0;
  vr1v = *(const u16x8*)vg1;
  *(u16x8*)kl0 = kr0v; *(u16x8*)kl1 = kr1v;
  *(u16x8*)vl0 = vr0v; *(u16x8*)vl1 = vr1v;
  __syncthreads();

  for (int kt = 0; kt < NT; ++kt) {
    if (kt + 1 < NT) {
      const size_t ko = (size_t)(kt + 1) * KB;
      kr0v = *(const u16x8*)(kg0 + ko * kDM);
      kr1v = *(const u16x8*)(kg1 + ko * kDM);
      vr0v = *(const u16x8*)(vg0 + ko);
      vr1v = *(const u16x8*)(vg1 + ko);
    }

    // --- QK^T (swapped: mfma(K, Q)) ---
    f32x4 sacc[2][4] = {};
#pragma unroll
    for (int cb = 0; cb < 4; ++cb) {
      const int n = cb * 16 + fr;
      bf16x8 kf[4];
#pragma unroll
      for (int kc = 0; kc < 4; ++kc) {
        const int d0 = kc * 4 + fq;
        kf[kc] = *(const bf16x8*)&Kls[n * 128 + (d0 ^ (n & 7)) * 8];
      }
      __builtin_amdgcn_s_setprio(1);
#pragma unroll
      for (int rb = 0; rb < 2; ++rb)
#pragma unroll
        for (int kc = 0; kc < 4; ++kc)
          sacc[rb][cb] = MFMA_BF16(kf[kc], qf[rb][kc], sacc[rb][cb]);
      __builtin_amdgcn_s_setprio(0);
    }

    // --- online softmax: lane owns row q=fr; keys = cb*16 + fq*4 + i ---
#pragma unroll
    for (int rb = 0; rb < 2; ++rb) {
      float m = sacc[rb][0][0];
#pragma unroll
      for (int cb = 0; cb < 4; ++cb)
#pragma unroll
        for (int i = 0; i < 4; ++i) m = fmaxf(m, sacc[rb][cb][i]);
      m = fmaxf(m, __shfl_xor(m, 16));
      m = fmaxf(m, __shfl_xor(m, 32));

      if (__any(m - mrun[rb] > THR)) {
        const float mnew = fmaxf(mrun[rb], m);
        const float sclS = exp2f(mrun[rb] - mnew);
        mrun[rb] = mnew;
        float scl[4];
#pragma unroll
        for (int i = 0; i < 4; ++i) scl[i] = __shfl(sclS, fq * 4 + i);
#pragma unroll
        for (int db = 0; db < 9; ++db)
#pragma unroll
          for (int i = 0; i < 4; ++i) oacc[rb][db][i] *= scl[i];
      }

#pragma unroll
      for (int cb = 0; cb < 4; ++cb) {
        u16x4 pk;
#pragma unroll
        for (int i = 0; i < 4; ++i)
          pk[i] = nbf(exp2f(sacc[rb][cb][i] - mrun[rb]));
        *(u16x4*)&Pls[w][rb * (16 * PST) + fr * PST + cb * 16 + fq * 4] = pk;
      }
    }

    asm volatile("s_waitcnt lgkmcnt(0)" ::: "memory");

    // --- PV (+ denom via ones-V) ---
    bf16x8 pf[2][2];
#pragma unroll
    for (int rb = 0; rb < 2; ++rb)
#pragma unroll
      for (int kb = 0; kb < 2; ++kb)
        pf[rb][kb] = *(const bf16x8*)&Pls[w][rb * (16 * PST) + fr * PST + kb * 32 + fq * 8];
#pragma unroll
    for (int db = 0; db < 8; ++db) {
      const int d = db * 16 + fr;
      bf16x8 vf0 = *(const bf16x8*)&Vt[d * KB + ((fq ^ (d & 7)) << 3)];
      bf16x8 vf1 = *(const bf16x8*)&Vt[d * KB + (((4 + fq) ^ (d & 7)) << 3)];
      __builtin_amdgcn_s_setprio(1);
#pragma unroll
      for (int rb = 0; rb < 2; ++rb) {
        oacc[rb][db] = MFMA_BF16(pf[rb][0], vf0, oacc[rb][db]);
        oacc[rb][db] = MFMA_BF16(pf[rb][1], vf1, oacc[rb][db]);
      }
      __builtin_amdgcn_s_setprio(0);
    }
    __builtin_amdgcn_s_setprio(1);
#pragma unroll
    for (int rb = 0; rb < 2; ++rb) {
      oacc[rb][8] = MFMA_BF16(pf[rb][0], ones, oacc[rb][8]);
      oacc[rb][8] = MFMA_BF16(pf[rb][1], ones, oacc[rb][8]);
    }
    __builtin_amdgcn_s_setprio(0);

    __syncthreads();
    if (kt + 1 < NT) {
      *(u16x8*)kl0 = kr0v; *(u16x8*)kl1 = kr1v;
      *(u16x8*)vl0 = vr0v; *(u16x8*)vl1 = vr1v;
    }
    __syncthreads();
  }

  u16* cbase = ctx + ((size_t)b * kS) * kDM + h * kD;
#pragma unroll
  for (int rb = 0; rb < 2; ++rb) {
    float inv[4];
#pragma unroll
    for (int i = 0; i < 4; ++i) inv[i] = 1.0f / oacc[rb][8][i];
#pragma unroll
    for (int db = 0; db < 8; ++db)
#pragma unroll
      for (int i = 0; i < 4; ++i) {
        const int row = q0 + w * 32 + rb * 16 + fq * 4 + i;
        const int col = db * 16 + fr;
        cbase[(size_t)row * kDM + col] = nbf(oacc[rb][db][i] * inv[i]);
      }
  }
}

// ---------------------------------------------------------------------------
extern "C" void kernel_launch(void* const* d_in, const int* in_sizes, int n_in,
                              void* d_out, int out_size, void* d_ws, size_t ws_size,
                              hipStream_t stream) {
  const float* q = (const float*)d_in[0];
  const float* k = (const float*)d_in[1];
  const float* v = (const float*)d_in[2];
  const float* Wq = (const float*)d_in[3];
  const float* Wk = (const float*)d_in[4];
  const float* Wv = (const float*)d_in[5];
  const float* Wo = (const float*)d_in[6];
  float* out = (float*)d_out;

  const size_t needFast = 11 * kMat * sizeof(u16);  // 7 bf16 inputs + qp/kp/vpT/ctx

  if (ws_size >= needFast) {
    u16* wsb = (u16*)d_ws;            // [0..6]: qb kb vb Wqb Wkb Wvb Wob
    u16* qp = wsb + 7 * kMat;
    u16* kp = wsb + 8 * kMat;
    u16* vpT = wsb + 9 * kMat;
    u16* ctx = wsb + 10 * kMat;

    cvt_kernel<<<dim3(1024, 7), 256, 0, stream>>>(q, k, v, Wq, Wk, Wv, Wo, wsb);
    proj_qk256_kernel<<<dim3(16, 16, 2), 512, 0, stream>>>(wsb, qp, kp);
    proj_vT256_kernel<<<dim3(16, 16), 512, 0, stream>>>(wsb, vpT);
    attn_kernel<<<dim3(8, 64), 512, 0, stream>>>(qp, kp, vpT, ctx);
    out_proj256_kernel<<<dim3(16, 16), 512, 0, stream>>>(ctx, wsb + 6 * kMat, out);
  } else {
    u16* qp = (u16*)d_ws;
    u16* kp = qp + kMat;
    u16* vpT = kp + kMat;
    u16* ctx = vpT + kMat;

    proj_qk_conv_kernel<<<dim3(32, 32, 2), 256, 0, stream>>>(q, k, Wq, Wk, qp, kp);
    proj_vT_conv_kernel<<<dim3(32, 32), 256, 0, stream>>>(v, Wv, vpT);
    attn_kernel<<<dim3(8, 64), 512, 0, stream>>>(qp, kp, vpT, ctx);
    out_proj_conv_kernel<<<dim3(32, 32, 1), 256, 0, stream>>>(ctx, Wo, out);
  }
}

// Round 14
// 732.227 us; speedup vs baseline: 1.8047x; 1.8047x over previous
//
#include <hip/hip_runtime.h>
#include <hip/hip_bf16.h>
#include <stdint.h>

// ============================================================================
// MultiHeadAttention: y = softmax((xq Wq^T)(xk Wk^T)^T * scale) (xv Wv^T) Wo^T
// B=2, S=2048, H=32, D=128, DM=4096. I/O float32.
// R14: GEMM reverted to R11 (constexpr dbuf unroll; no reg-pipeline — R12/R13
// spilled at the 128-VGPR cap) with ONE change: single barrier per phase
// (after the MFMA cluster). The mid-phase barrier forced all waves to finish
// ds_reads before any MFMA, forbidding the 2-wave/SIMD LDS||MFMA overlap;
// correctness needs only >=1 barrier between a region's last reads and its
// re-stage, which phase-end barriers provide. Attn (R9) and cvt unchanged.
// ============================================================================

using u16 = unsigned short;
using u32 = unsigned int;

typedef __attribute__((ext_vector_type(8))) short bf16x8;  // MFMA A/B frag (8 bf16)
typedef __attribute__((ext_vector_type(8))) u16 u16x8;
typedef __attribute__((ext_vector_type(4))) u16 u16x4;
typedef __attribute__((ext_vector_type(4))) float f32x4;   // MFMA C/D frag

#define MFMA_BF16(A, B, C) __builtin_amdgcn_mfma_f32_16x16x32_bf16((A), (B), (C), 0, 0, 0)

static constexpr int kS = 2048, kDM = 4096, kD = 128;
static constexpr size_t kMat = (size_t)4096 * 4096;
// SCALE * log2(e): softmax computed in exp2 domain
static constexpr float kScaleLog2e = 0.08838834764831845f * 1.44269504088896340736f;

static __device__ __forceinline__ void gload_lds16(const u16* g, u16* l) {
  __builtin_amdgcn_global_load_lds((const __attribute__((address_space(1))) void*)g,
                                   (__attribute__((address_space(3))) void*)l, 16, 0, 0);
}

static __device__ __forceinline__ u16 f2bf(float f) {  // RNE f32 -> bf16 bits (sw)
  u32 u = __float_as_uint(f);
  u32 r = u + 0x7FFFu + ((u >> 16) & 1u);
  return (u16)(r >> 16);
}

static __device__ __forceinline__ float bf2f(u16 x) {  // exact bf16 -> f32
  return __uint_as_float((u32)x << 16);
}

static __device__ __forceinline__ u16 nbf(float f) {  // native cast (hw cvt)
  union { __hip_bfloat16 h; u16 u; } cv;
  cv.h = __float2bfloat16(f);
  return cv.u;
}

static __device__ __forceinline__ u16x8 cvt8(float4 a, float4 b) {
  u16x8 r;
  r[0] = f2bf(a.x); r[1] = f2bf(a.y); r[2] = f2bf(a.z); r[3] = f2bf(a.w);
  r[4] = f2bf(b.x); r[5] = f2bf(b.y); r[6] = f2bf(b.z); r[7] = f2bf(b.w);
  return r;
}

// ---------------------------------------------------------------------------
// f32 -> bf16 bulk conversion: 7 matrices of kMat elems. Grid (X, 7).
// ---------------------------------------------------------------------------
__global__ __launch_bounds__(256) void cvt_kernel(
    const float* __restrict__ s0, const float* __restrict__ s1,
    const float* __restrict__ s2, const float* __restrict__ s3,
    const float* __restrict__ s4, const float* __restrict__ s5,
    const float* __restrict__ s6, u16* __restrict__ dst) {
  const int y = blockIdx.y;
  const float* s = (y == 0) ? s0 : (y == 1) ? s1 : (y == 2) ? s2 : (y == 3) ? s3
                  : (y == 4) ? s4 : (y == 5) ? s5 : s6;
  u16* d = dst + (size_t)y * kMat;
  const size_t nchunk = kMat / 8;
  const size_t step = (size_t)gridDim.x * 256;
  for (size_t c = (size_t)blockIdx.x * 256 + threadIdx.x; c < nchunk; c += step) {
    const float* p = s + c * 8;
    float4 a = *(const float4*)p;
    float4 b = *(const float4*)(p + 4);
    *(u16x8*)(d + c * 8) = cvt8(a, b);
  }
}

// ---------------------------------------------------------------------------
// 256x256 8-phase GEMM (R11 structure, single barrier per phase).
// Y[m][n] = sum_k X[m][k]*W[n][k]. 512 thr = 8 waves, per-wave 128x64,
// BK=64, 128KB LDS dbuf, constexpr dbuf offsets. vmcnt(6) once per K-tile.
// ---------------------------------------------------------------------------
template <bool TRANS, bool OUT_F32>
static __device__ __forceinline__ void gemm256(const u16* __restrict__ X,
                                               const u16* __restrict__ W,
                                               void* __restrict__ Yv,
                                               u16* __restrict__ lds,
                                               int m0, int n0) {
  constexpr int NT = kDM / 64;
  const int tid = threadIdx.x;
  const int lane = tid & 63;
  const int w = tid >> 6;
  const int fr = lane & 15;
  const int fq = lane >> 4;
  const int wr = w >> 2;  // 0..1  (M half)
  const int wc = w & 3;   // 0..3  (N quarter)

  const int srow = tid >> 3;
  const int scol = ((tid & 7) ^ (srow & 7)) * 8;
  const u16* Xrow = X + (size_t)(m0 + srow) * kDM + scol;
  const u16* Wrow = W + (size_t)(n0 + srow) * kDM + scol;
  const int w512 = w * 512;

  const int rBb = wc * 64 + fr;
  const int rAb = wr * 128 + fr;
  const int swz = fr & 7;

  f32x4 acc[8][4] = {};

#define STAGE2(ROWP, qrow, k0, ldq)                                        \
  do {                                                                     \
    gload_lds16((ROWP) + (size_t)(qrow) * kDM + (k0), &lds[(ldq) + w512]); \
    gload_lds16((ROWP) + (size_t)((qrow) + 64) * kDM + (k0),               \
                &lds[(ldq) + 4096 + w512]);                                \
  } while (0)

#define RD_B(BOFF, nf, ks) \
  (*(const bf16x8*)&lds[(BOFF) + (rBb + (nf) * 16) * 64 + ((((ks) * 4 + fq) ^ swz) * 8)])
#define RD_A(AOFF, mi, ks) \
  (*(const bf16x8*)&lds[(AOFF) + (rAb + (mi) * 16) * 64 + ((((ks) * 4 + fq) ^ swz) * 8)])

#define CLUSTER(mia)                                                            \
  do {                                                                          \
    __builtin_amdgcn_s_setprio(1);                                              \
    _Pragma("unroll") for (int mj = 0; mj < 2; ++mj)                            \
    _Pragma("unroll") for (int nf = 0; nf < 4; ++nf)                            \
    _Pragma("unroll") for (int ks = 0; ks < 2; ++ks)                            \
      acc[(mia) + mj][nf] =                                                     \
          TRANS ? MFMA_BF16(bfr[nf][ks], af[mj][ks], acc[(mia) + mj][nf])       \
                : MFMA_BF16(af[mj][ks], bfr[nf][ks], acc[(mia) + mj][nf]);      \
    __builtin_amdgcn_s_setprio(0);                                              \
  } while (0)

// One K-tile, compile-time dbuf DC. Single barrier per phase (at phase end):
// within a phase, waves that finish their ds_reads early can start MFMA while
// others still read (2 waves/SIMD LDS||MFMA overlap). Region-safety: every
// staged region's last reads are >=1 phase-end barrier before the stage.
#define KTILE(DC, t)                                                           \
  {                                                                            \
    constexpr int Boff = (DC) * 32768;                                         \
    constexpr int Aoff = Boff + 16384;                                         \
    bf16x8 bfr[4][2], af[2][2];                                                \
    /* p0: read B(8)+A[0,1](4); stage A1(t+1); c0; barrier */                  \
    _Pragma("unroll") for (int nf = 0; nf < 4; ++nf)                           \
    _Pragma("unroll") for (int ks = 0; ks < 2; ++ks)                           \
      bfr[nf][ks] = RD_B(Boff, nf, ks);                                        \
    _Pragma("unroll") for (int mj = 0; mj < 2; ++mj)                           \
    _Pragma("unroll") for (int ks = 0; ks < 2; ++ks)                           \
      af[mj][ks] = RD_A(Aoff, mj, ks);                                         \
    if ((t) + 1 < NT)                                                          \
      STAGE2(Xrow, 128, ((t) + 1) * 64, ((DC) ^ 1) * 32768 + 24576);           \
    CLUSTER(0);                                                                \
    __builtin_amdgcn_s_barrier();                                              \
    /* p1: read A[2,3]; stage B0(t+2); c2; barrier */                          \
    _Pragma("unroll") for (int mj = 0; mj < 2; ++mj)                           \
    _Pragma("unroll") for (int ks = 0; ks < 2; ++ks)                           \
      af[mj][ks] = RD_A(Aoff, 2 + mj, ks);                                     \
    if ((t) + 2 < NT) STAGE2(Wrow, 0, ((t) + 2) * 64, Boff + 0);               \
    CLUSTER(2);                                                                \
    __builtin_amdgcn_s_barrier();                                              \
    /* p2: read A[4,5]; stage B1(t+2); c4; barrier */                          \
    _Pragma("unroll") for (int mj = 0; mj < 2; ++mj)                           \
    _Pragma("unroll") for (int ks = 0; ks < 2; ++ks)                           \
      af[mj][ks] = RD_A(Aoff, 4 + mj, ks);                                     \
    if ((t) + 2 < NT) STAGE2(Wrow, 128, ((t) + 2) * 64, Boff + 8192);          \
    CLUSTER(4);                                                                \
    __builtin_amdgcn_s_barrier();                                              \
    /* p3: read A[6,7]; stage A0(t+2); c6; vmcnt; barrier */                   \
    _Pragma("unroll") for (int mj = 0; mj < 2; ++mj)                           \
    _Pragma("unroll") for (int ks = 0; ks < 2; ++ks)                           \
      af[mj][ks] = RD_A(Aoff, 6 + mj, ks);                                     \
    if ((t) + 2 < NT) STAGE2(Xrow, 0, ((t) + 2) * 64, Boff + 16384);           \
    CLUSTER(6);                                                                \
    if ((t) + 2 < NT)                                                          \
      asm volatile("s_waitcnt vmcnt(6)" ::: "memory");                         \
    else                                                                       \
      asm volatile("s_waitcnt vmcnt(0)" ::: "memory");                         \
    __builtin_amdgcn_s_barrier();                                              \
  }

  // prologue: t0 {B0,B1,A0,A1} dbuf0; t1 {B0,B1,A0} dbuf1; A1(t1) at p0(t0).
  STAGE2(Wrow, 0, 0, 0);
  STAGE2(Wrow, 128, 0, 8192);
  STAGE2(Xrow, 0, 0, 16384);
  STAGE2(Xrow, 128, 0, 24576);
  STAGE2(Wrow, 0, 64, 32768);
  STAGE2(Wrow, 128, 64, 32768 + 8192);
  STAGE2(Xrow, 0, 64, 32768 + 16384);
  asm volatile("s_waitcnt vmcnt(6)" ::: "memory");
  __builtin_amdgcn_s_barrier();

  for (int tt = 0; tt < NT; tt += 2) {
    KTILE(0, tt);
    KTILE(1, tt + 1);
  }
#undef KTILE
#undef CLUSTER
#undef RD_A
#undef RD_B
#undef STAGE2

  // epilogue: C/D layout col=lane&15, row=(lane>>4)*4+i [m89/m91]
#pragma unroll
  for (int mi = 0; mi < 8; ++mi)
#pragma unroll
    for (int nf = 0; nf < 4; ++nf) {
      int row, col;
      if constexpr (TRANS) {
        row = n0 + wc * 64 + nf * 16 + fq * 4;
        col = m0 + wr * 128 + mi * 16 + fr;
      } else {
        row = m0 + wr * 128 + mi * 16 + fq * 4;
        col = n0 + wc * 64 + nf * 16 + fr;
      }
      if constexpr (OUT_F32) {
        float* yp = (float*)Yv + (size_t)row * kDM + col;
#pragma unroll
        for (int i = 0; i < 4; ++i) yp[(size_t)i * kDM] = acc[mi][nf][i];
      } else {
        u16* yp = (u16*)Yv + (size_t)row * kDM + col;
#pragma unroll
        for (int i = 0; i < 4; ++i) yp[(size_t)i * kDM] = f2bf(acc[mi][nf][i]);
      }
    }
}

// XCD-aware bijective remap (hw flat id -> work id; 8 XCDs, nwg%8==0)
static __device__ __forceinline__ int xcd_swz(int id, int cpx) {
  return (id & 7) * cpx + (id >> 3);
}

__global__ __launch_bounds__(512, 2) void proj_qk256_kernel(const u16* __restrict__ wsb,
                                                            u16* __restrict__ qp,
                                                            u16* __restrict__ kp) {
  __shared__ u16 lds[65536];
  const int z = blockIdx.z;
  const int s = xcd_swz(blockIdx.y * 16 + blockIdx.x, 32);
  const int m0 = (s >> 4) * 256, n0 = (s & 15) * 256;
  gemm256<false, false>(wsb + (size_t)z * kMat, wsb + (size_t)(3 + z) * kMat,
                        z ? kp : qp, lds, m0, n0);
}

__global__ __launch_bounds__(512, 2) void proj_vT256_kernel(const u16* __restrict__ wsb,
                                                            u16* __restrict__ vpT) {
  __shared__ u16 lds[65536];
  const int s = xcd_swz(blockIdx.y * 16 + blockIdx.x, 32);
  gemm256<true, false>(wsb + 2 * kMat, wsb + 5 * kMat, vpT, lds,
                       (s >> 4) * 256, (s & 15) * 256);
}

__global__ __launch_bounds__(512, 2) void out_proj256_kernel(const u16* __restrict__ ctx,
                                                             const u16* __restrict__ Wob,
                                                             float* __restrict__ out) {
  __shared__ u16 lds[65536];
  const int s = xcd_swz(blockIdx.y * 16 + blockIdx.x, 32);
  gemm256<false, true>(ctx, Wob, out, lds, (s >> 4) * 256, (s & 15) * 256);
}

// ---------------------------------------------------------------------------
// FALLBACK path (ws too small): in-GEMM convert staging (R5-verified).
// ---------------------------------------------------------------------------
template <bool A_BF16, bool TRANS, bool OUT_F32>
static __device__ __forceinline__ void gemm_conv(const void* Xv, const float* Wf,
                                                 void* Yv, u16* __restrict__ Als,
                                                 u16* __restrict__ Bls) {
  constexpr int KD = 4096;
  const int tid = threadIdx.x;
  const int lane = tid & 63;
  const int w = tid >> 6;
  const int fr = lane & 15;
  const int fq = lane >> 4;
  const int m0 = blockIdx.y * 128;
  const int n0 = blockIdx.x * 128;

  const int r0 = tid >> 2, cc0 = (tid & 3) * 8;
  const int r1 = r0 + 64;
  const int sr = lane >> 2, sc = (lane & 3) * 8;
  const int u0 = w * 2, u1 = w * 2 + 1;

  const u16* Xb = (const u16*)Xv;
  const float* Xf = (const float*)Xv;

  const int wm = (w >> 1) * 64;
  const int wn = (w & 1) * 64;

  f32x4 acc[4][4] = {};

  for (int kt = 0; kt < KD / 32; ++kt) {
    const int ko = kt * 32;
    if constexpr (A_BF16) {
      gload_lds16(Xb + (size_t)(m0 + u0 * 16 + sr) * KD + ko + sc, &Als[u0 * 512]);
      gload_lds16(Xb + (size_t)(m0 + u1 * 16 + sr) * KD + ko + sc, &Als[u1 * 512]);
    } else {
      const float* p0 = Xf + (size_t)(m0 + r0) * KD + ko + cc0;
      const float* p1 = Xf + (size_t)(m0 + r1) * KD + ko + cc0;
      float4 a0 = *(const float4*)(p0);
      float4 a1 = *(const float4*)(p0 + 4);
      float4 a2 = *(const float4*)(p1);
      float4 a3 = *(const float4*)(p1 + 4);
      *(u16x8*)&Als[r0 * 32 + cc0] = cvt8(a0, a1);
      *(u16x8*)&Als[r1 * 32 + cc0] = cvt8(a2, a3);
    }
    {
      const float* p0 = Wf + (size_t)(n0 + r0) * KD + ko + cc0;
      const float* p1 = Wf + (size_t)(n0 + r1) * KD + ko + cc0;
      float4 b0 = *(const float4*)(p0);
      float4 b1 = *(const float4*)(p0 + 4);
      float4 b2 = *(const float4*)(p1);
      float4 b3 = *(const float4*)(p1 + 4);
      *(u16x8*)&Bls[r0 * 32 + cc0] = cvt8(b0, b1);
      *(u16x8*)&Bls[r1 * 32 + cc0] = cvt8(b2, b3);
    }
    __syncthreads();

    bf16x8 af[4], bfv[4];
#pragma unroll
    for (int i = 0; i < 4; ++i)
      af[i] = *(const bf16x8*)&Als[(wm + i * 16 + fr) * 32 + fq * 8];
#pragma unroll
    for (int i = 0; i < 4; ++i)
      bfv[i] = *(const bf16x8*)&Bls[(wn + i * 16 + fr) * 32 + fq * 8];
#pragma unroll
    for (int a = 0; a < 4; ++a)
#pragma unroll
      for (int bb = 0; bb < 4; ++bb) {
        if constexpr (TRANS)
          acc[a][bb] = MFMA_BF16(bfv[a], af[bb], acc[a][bb]);
        else
          acc[a][bb] = MFMA_BF16(af[a], bfv[bb], acc[a][bb]);
      }
    __syncthreads();
  }

#pragma unroll
  for (int a = 0; a < 4; ++a)
#pragma unroll
    for (int bb = 0; bb < 4; ++bb) {
      const int row = TRANS ? (n0 + wn + a * 16 + fq * 4) : (m0 + wm + a * 16 + fq * 4);
      const int col = TRANS ? (m0 + wm + bb * 16 + fr) : (n0 + wn + bb * 16 + fr);
      if constexpr (OUT_F32) {
        float* yp = (float*)Yv + (size_t)row * kDM + col;
#pragma unroll
        for (int i = 0; i < 4; ++i) yp[(size_t)i * kDM] = acc[a][bb][i];
      } else {
        u16* yp = (u16*)Yv + (size_t)row * kDM + col;
#pragma unroll
        for (int i = 0; i < 4; ++i) yp[(size_t)i * kDM] = f2bf(acc[a][bb][i]);
      }
    }
}

__global__ __launch_bounds__(256) void proj_qk_conv_kernel(
    const float* __restrict__ q, const float* __restrict__ k,
    const float* __restrict__ Wq, const float* __restrict__ Wk,
    u16* __restrict__ qp, u16* __restrict__ kp) {
  __shared__ u16 Als[128 * 32];
  __shared__ u16 Bls[128 * 32];
  const int z = blockIdx.z;
  gemm_conv<false, false, false>(z ? k : q, z ? Wk : Wq, z ? kp : qp, Als, Bls);
}

__global__ __launch_bounds__(256) void proj_vT_conv_kernel(
    const float* __restrict__ v, const float* __restrict__ Wv, u16* __restrict__ vpT) {
  __shared__ u16 Als[128 * 32];
  __shared__ u16 Bls[128 * 32];
  gemm_conv<false, true, false>(v, Wv, vpT, Als, Bls);
}

__global__ __launch_bounds__(256) void out_proj_conv_kernel(const u16* __restrict__ ctx,
                                                            const float* __restrict__ Wo,
                                                            float* __restrict__ out) {
  __shared__ u16 Als[128 * 32];
  __shared__ u16 Bls[128 * 32];
  gemm_conv<true, false, true>(ctx, Wo, out, Als, Bls);
}

// ---------------------------------------------------------------------------
// Flash attention (R9, unchanged): grid (8,64) block 512 = 8 waves.
// Swapped QK^T; conflict-free b64 P-stores; ones-V denom; defer-max;
// reg-staged async K/V prefetch; XCD swizzle.
// ---------------------------------------------------------------------------
__global__ __launch_bounds__(512) void attn_kernel(const u16* __restrict__ qp,
                                                   const u16* __restrict__ kp,
                                                   const u16* __restrict__ vpT,
                                                   u16* __restrict__ ctx) {
  constexpr int KB = 64;
  constexpr int NT = kS / KB;   // 32 tiles
  constexpr int PST = 72;       // P row stride (elems, 16B-aligned rows)
  constexpr float THR = 11.5f;  // defer-max threshold (log2 units ~ e^8)

  __shared__ u16 Kls[KB * 128];        // 16 KB [key][d] chunk-swizzled
  __shared__ u16 Vt[kD * KB];          // 16 KB [d][key] chunk-swizzled
  __shared__ u16 Pls[8][2 * 16 * PST]; // 36 KB per-wave P tiles [q][key]

  const int tid = threadIdx.x, lane = tid & 63, w = tid >> 6;  // w: 0..7
  const int fr = lane & 15, fq = lane >> 4;

  const int wg = blockIdx.y * 8 + blockIdx.x;
  const int o = (wg & 7) * 64 + (wg >> 3);
  const int bh = o >> 3;
  const int b = bh >> 5, h = bh & 31;
  const int q0 = (o & 7) * 256;

  const u16* qbase = qp + ((size_t)b * kS) * kDM + h * kD;
  const u16* kbase = kp + ((size_t)b * kS) * kDM + h * kD;
  const u16* vtbase = vpT + (size_t)(h * kD) * kDM + b * kS;  // row d, stride kDM

  bf16x8 qf[2][4];
#pragma unroll
  for (int rb = 0; rb < 2; ++rb)
#pragma unroll
    for (int kc = 0; kc < 4; ++kc) {
      const u16x8 raw = *(const u16x8*)(qbase +
          (size_t)(q0 + w * 32 + rb * 16 + fr) * kDM + kc * 32 + fq * 8);
      bf16x8 s;
#pragma unroll
      for (int j = 0; j < 8; ++j) s[j] = (short)f2bf(bf2f(raw[j]) * kScaleLog2e);
      qf[rb][kc] = s;
    }

  f32x4 oacc[2][9] = {};
  float mrun[2] = {-1e30f, -1e30f};

  bf16x8 ones;
#pragma unroll
  for (int j = 0; j < 8; ++j) ones[j] = (short)0x3F80;  // bf16 1.0

  const int krl = lane >> 4, kdp = lane & 15;
  const int vdl = lane >> 3, vc = lane & 7;
  const int rk0 = (w * 2 + 0) * 4 + krl;
  const int rk1 = (w * 2 + 1) * 4 + krl;
  const int dv0 = (w * 2 + 0) * 8 + vdl;
  const int dv1 = (w * 2 + 1) * 8 + vdl;
  const u16* kg0 = kbase + (size_t)rk0 * kDM + kdp * 8;
  const u16* kg1 = kbase + (size_t)rk1 * kDM + kdp * 8;
  const u16* vg0 = vtbase + (size_t)dv0 * kDM + vc * 8;
  const u16* vg1 = vtbase + (size_t)dv1 * kDM + vc * 8;
  u16* kl0 = &Kls[rk0 * 128 + ((kdp ^ (rk0 & 7)) * 8)];
  u16* kl1 = &Kls[rk1 * 128 + ((kdp ^ (rk1 & 7)) * 8)];
  u16* vl0 = &Vt[dv0 * KB + ((vc ^ (dv0 & 7)) * 8)];
  u16* vl1 = &Vt[dv1 * KB + ((vc ^ (dv1 & 7)) * 8)];

  u16x8 kr0v, kr1v, vr0v, vr1v;
  kr0v = *(const u16x8*)kg0;
  kr1v = *(const u16x8*)kg1;
  vr0v = *(const u16x8*)vg0;
  vr1v = *(const u16x8*)vg1;
  *(u16x8*)kl0 = kr0v; *(u16x8*)kl1 = kr1v;
  *(u16x8*)vl0 = vr0v; *(u16x8*)vl1 = vr1v;
  __syncthreads();

  for (int kt = 0; kt < NT; ++kt) {
    if (kt + 1 < NT) {
      const size_t ko = (size_t)(kt + 1) * KB;
      kr0v = *(const u16x8*)(kg0 + ko * kDM);
      kr1v = *(const u16x8*)(kg1 + ko * kDM);
      vr0v = *(const u16x8*)(vg0 + ko);
      vr1v = *(const u16x8*)(vg1 + ko);
    }

    // --- QK^T (swapped: mfma(K, Q)) ---
    f32x4 sacc[2][4] = {};
#pragma unroll
    for (int cb = 0; cb < 4; ++cb) {
      const int n = cb * 16 + fr;
      bf16x8 kf[4];
#pragma unroll
      for (int kc = 0; kc < 4; ++kc) {
        const int d0 = kc * 4 + fq;
        kf[kc] = *(const bf16x8*)&Kls[n * 128 + (d0 ^ (n & 7)) * 8];
      }
      __builtin_amdgcn_s_setprio(1);
#pragma unroll
      for (int rb = 0; rb < 2; ++rb)
#pragma unroll
        for (int kc = 0; kc < 4; ++kc)
          sacc[rb][cb] = MFMA_BF16(kf[kc], qf[rb][kc], sacc[rb][cb]);
      __builtin_amdgcn_s_setprio(0);
    }

    // --- online softmax: lane owns row q=fr; keys = cb*16 + fq*4 + i ---
#pragma unroll
    for (int rb = 0; rb < 2; ++rb) {
      float m = sacc[rb][0][0];
#pragma unroll
      for (int cb = 0; cb < 4; ++cb)
#pragma unroll
        for (int i = 0; i < 4; ++i) m = fmaxf(m, sacc[rb][cb][i]);
      m = fmaxf(m, __shfl_xor(m, 16));
      m = fmaxf(m, __shfl_xor(m, 32));

      if (__any(m - mrun[rb] > THR)) {
        const float mnew = fmaxf(mrun[rb], m);
        const float sclS = exp2f(mrun[rb] - mnew);
        mrun[rb] = mnew;
        float scl[4];
#pragma unroll
        for (int i = 0; i < 4; ++i) scl[i] = __shfl(sclS, fq * 4 + i);
#pragma unroll
        for (int db = 0; db < 9; ++db)
#pragma unroll
          for (int i = 0; i < 4; ++i) oacc[rb][db][i] *= scl[i];
      }

#pragma unroll
      for (int cb = 0; cb < 4; ++cb) {
        u16x4 pk;
#pragma unroll
        for (int i = 0; i < 4; ++i)
          pk[i] = nbf(exp2f(sacc[rb][cb][i] - mrun[rb]));
        *(u16x4*)&Pls[w][rb * (16 * PST) + fr * PST + cb * 16 + fq * 4] = pk;
      }
    }

    asm volatile("s_waitcnt lgkmcnt(0)" ::: "memory");

    // --- PV (+ denom via ones-V) ---
    bf16x8 pf[2][2];
#pragma unroll
    for (int rb = 0; rb < 2; ++rb)
#pragma unroll
      for (int kb = 0; kb < 2; ++kb)
        pf[rb][kb] = *(const bf16x8*)&Pls[w][rb * (16 * PST) + fr * PST + kb * 32 + fq * 8];
#pragma unroll
    for (int db = 0; db < 8; ++db) {
      const int d = db * 16 + fr;
      bf16x8 vf0 = *(const bf16x8*)&Vt[d * KB + ((fq ^ (d & 7)) << 3)];
      bf16x8 vf1 = *(const bf16x8*)&Vt[d * KB + (((4 + fq) ^ (d & 7)) << 3)];
      __builtin_amdgcn_s_setprio(1);
#pragma unroll
      for (int rb = 0; rb < 2; ++rb) {
        oacc[rb][db] = MFMA_BF16(pf[rb][0], vf0, oacc[rb][db]);
        oacc[rb][db] = MFMA_BF16(pf[rb][1], vf1, oacc[rb][db]);
      }
      __builtin_amdgcn_s_setprio(0);
    }
    __builtin_amdgcn_s_setprio(1);
#pragma unroll
    for (int rb = 0; rb < 2; ++rb) {
      oacc[rb][8] = MFMA_BF16(pf[rb][0], ones, oacc[rb][8]);
      oacc[rb][8] = MFMA_BF16(pf[rb][1], ones, oacc[rb][8]);
    }
    __builtin_amdgcn_s_setprio(0);

    __syncthreads();
    if (kt + 1 < NT) {
      *(u16x8*)kl0 = kr0v; *(u16x8*)kl1 = kr1v;
      *(u16x8*)vl0 = vr0v; *(u16x8*)vl1 = vr1v;
    }
    __syncthreads();
  }

  u16* cbase = ctx + ((size_t)b * kS) * kDM + h * kD;
#pragma unroll
  for (int rb = 0; rb < 2; ++rb) {
    float inv[4];
#pragma unroll
    for (int i = 0; i < 4; ++i) inv[i] = 1.0f / oacc[rb][8][i];
#pragma unroll
    for (int db = 0; db < 8; ++db)
#pragma unroll
      for (int i = 0; i < 4; ++i) {
        const int row = q0 + w * 32 + rb * 16 + fq * 4 + i;
        const int col = db * 16 + fr;
        cbase[(size_t)row * kDM + col] = nbf(oacc[rb][db][i] * inv[i]);
      }
  }
}

// ---------------------------------------------------------------------------
extern "C" void kernel_launch(void* const* d_in, const int* in_sizes, int n_in,
                              void* d_out, int out_size, void* d_ws, size_t ws_size,
                              hipStream_t stream) {
  const float* q = (const float*)d_in[0];
  const float* k = (const float*)d_in[1];
  const float* v = (const float*)d_in[2];
  const float* Wq = (const float*)d_in[3];
  const float* Wk = (const float*)d_in[4];
  const float* Wv = (const float*)d_in[5];
  const float* Wo = (const float*)d_in[6];
  float* out = (float*)d_out;

  const size_t needFast = 11 * kMat * sizeof(u16);  // 7 bf16 inputs + qp/kp/vpT/ctx

  if (ws_size >= needFast) {
    u16* wsb = (u16*)d_ws;            // [0..6]: qb kb vb Wqb Wkb Wvb Wob
    u16* qp = wsb + 7 * kMat;
    u16* kp = wsb + 8 * kMat;
    u16* vpT = wsb + 9 * kMat;
    u16* ctx = wsb + 10 * kMat;

    cvt_kernel<<<dim3(1024, 7), 256, 0, stream>>>(q, k, v, Wq, Wk, Wv, Wo, wsb);
    proj_qk256_kernel<<<dim3(16, 16, 2), 512, 0, stream>>>(wsb, qp, kp);
    proj_vT256_kernel<<<dim3(16, 16), 512, 0, stream>>>(wsb, vpT);
    attn_kernel<<<dim3(8, 64), 512, 0, stream>>>(qp, kp, vpT, ctx);
    out_proj256_kernel<<<dim3(16, 16), 512, 0, stream>>>(ctx, wsb + 6 * kMat, out);
  } else {
    u16* qp = (u16*)d_ws;
    u16* kp = qp + kMat;
    u16* vpT = kp + kMat;
    u16* ctx = vpT + kMat;

    proj_qk_conv_kernel<<<dim3(32, 32, 2), 256, 0, stream>>>(q, k, Wq, Wk, qp, kp);
    proj_vT_conv_kernel<<<dim3(32, 32), 256, 0, stream>>>(v, Wv, vpT);
    attn_kernel<<<dim3(8, 64), 512, 0, stream>>>(qp, kp, vpT, ctx);
    out_proj_conv_kernel<<<dim3(32, 32, 1), 256, 0, stream>>>(ctx, Wo, out);
  }
}

// Round 16
// 724.978 us; speedup vs baseline: 1.8227x; 1.0100x over previous
//
#include <hip/hip_runtime.h>
#include <hip/hip_bf16.h>
#include <stdint.h>

// ============================================================================
// MultiHeadAttention: y = softmax((xq Wq^T)(xk Wk^T)^T * scale) (xv Wv^T) Wo^T
// B=2, S=2048, H=32, D=128, DM=4096. I/O float32.
// R16: fixes R15's race. Ledger: entering tile t with 4 in flight {B(t+1)};
// stages A0(t+1)@p0, A1(t+1)@p1, B0(t+2)@p2, B1(t+2)@p3 -> 12 at p3-end.
// R15's vmcnt(6) left A1(t+1) in flight while wr=1 waves read the A1 region
// at t+1 p0 (A1 is read in EVERY phase by wr=1, not just p2/p3). Fix:
// vmcnt(4) at p3-end (drains B(t+1)+A0/A1(t+1), leaves {B(t+2)}=4); drop
// the no-op p1 vmcnt. Two barriers per K-tile kept. Attn (R9), cvt unchanged.
// ============================================================================

using u16 = unsigned short;
using u32 = unsigned int;

typedef __attribute__((ext_vector_type(8))) short bf16x8;  // MFMA A/B frag (8 bf16)
typedef __attribute__((ext_vector_type(8))) u16 u16x8;
typedef __attribute__((ext_vector_type(4))) u16 u16x4;
typedef __attribute__((ext_vector_type(4))) float f32x4;   // MFMA C/D frag

#define MFMA_BF16(A, B, C) __builtin_amdgcn_mfma_f32_16x16x32_bf16((A), (B), (C), 0, 0, 0)

static constexpr int kS = 2048, kDM = 4096, kD = 128;
static constexpr size_t kMat = (size_t)4096 * 4096;
// SCALE * log2(e): softmax computed in exp2 domain
static constexpr float kScaleLog2e = 0.08838834764831845f * 1.44269504088896340736f;

static __device__ __forceinline__ void gload_lds16(const u16* g, u16* l) {
  __builtin_amdgcn_global_load_lds((const __attribute__((address_space(1))) void*)g,
                                   (__attribute__((address_space(3))) void*)l, 16, 0, 0);
}

static __device__ __forceinline__ u16 f2bf(float f) {  // RNE f32 -> bf16 bits (sw)
  u32 u = __float_as_uint(f);
  u32 r = u + 0x7FFFu + ((u >> 16) & 1u);
  return (u16)(r >> 16);
}

static __device__ __forceinline__ float bf2f(u16 x) {  // exact bf16 -> f32
  return __uint_as_float((u32)x << 16);
}

static __device__ __forceinline__ u16 nbf(float f) {  // native cast (hw cvt)
  union { __hip_bfloat16 h; u16 u; } cv;
  cv.h = __float2bfloat16(f);
  return cv.u;
}

static __device__ __forceinline__ u16x8 cvt8(float4 a, float4 b) {
  u16x8 r;
  r[0] = f2bf(a.x); r[1] = f2bf(a.y); r[2] = f2bf(a.z); r[3] = f2bf(a.w);
  r[4] = f2bf(b.x); r[5] = f2bf(b.y); r[6] = f2bf(b.z); r[7] = f2bf(b.w);
  return r;
}

// ---------------------------------------------------------------------------
// f32 -> bf16 bulk conversion: 7 matrices of kMat elems. Grid (X, 7).
// ---------------------------------------------------------------------------
__global__ __launch_bounds__(256) void cvt_kernel(
    const float* __restrict__ s0, const float* __restrict__ s1,
    const float* __restrict__ s2, const float* __restrict__ s3,
    const float* __restrict__ s4, const float* __restrict__ s5,
    const float* __restrict__ s6, u16* __restrict__ dst) {
  const int y = blockIdx.y;
  const float* s = (y == 0) ? s0 : (y == 1) ? s1 : (y == 2) ? s2 : (y == 3) ? s3
                  : (y == 4) ? s4 : (y == 5) ? s5 : s6;
  u16* d = dst + (size_t)y * kMat;
  const size_t nchunk = kMat / 8;
  const size_t step = (size_t)gridDim.x * 256;
  for (size_t c = (size_t)blockIdx.x * 256 + threadIdx.x; c < nchunk; c += step) {
    const float* p = s + c * 8;
    float4 a = *(const float4*)p;
    float4 b = *(const float4*)(p + 4);
    *(u16x8*)(d + c * 8) = cvt8(a, b);
  }
}

// ---------------------------------------------------------------------------
// 256x256 GEMM, 2 barriers per K-tile (race-fixed). Y[m][n] = sum X*W^T.
// 512 thr = 8 waves, per-wave 128x64, BK=64, 128KB LDS dbuf, constexpr
// dbuf offsets.
// ---------------------------------------------------------------------------
template <bool TRANS, bool OUT_F32>
static __device__ __forceinline__ void gemm256(const u16* __restrict__ X,
                                               const u16* __restrict__ W,
                                               void* __restrict__ Yv,
                                               u16* __restrict__ lds,
                                               int m0, int n0) {
  constexpr int NT = kDM / 64;
  const int tid = threadIdx.x;
  const int lane = tid & 63;
  const int w = tid >> 6;
  const int fr = lane & 15;
  const int fq = lane >> 4;
  const int wr = w >> 2;  // 0..1  (M half)
  const int wc = w & 3;   // 0..3  (N quarter)

  const int srow = tid >> 3;
  const int scol = ((tid & 7) ^ (srow & 7)) * 8;
  const u16* Xrow = X + (size_t)(m0 + srow) * kDM + scol;
  const u16* Wrow = W + (size_t)(n0 + srow) * kDM + scol;
  const int w512 = w * 512;

  const int rBb = wc * 64 + fr;
  const int rAb = wr * 128 + fr;
  const int swz = fr & 7;

  f32x4 acc[8][4] = {};

#define STAGE2(ROWP, qrow, k0, ldq)                                        \
  do {                                                                     \
    gload_lds16((ROWP) + (size_t)(qrow) * kDM + (k0), &lds[(ldq) + w512]); \
    gload_lds16((ROWP) + (size_t)((qrow) + 64) * kDM + (k0),               \
                &lds[(ldq) + 4096 + w512]);                                \
  } while (0)

#define RD_B(BOFF, nf, ks) \
  (*(const bf16x8*)&lds[(BOFF) + (rBb + (nf) * 16) * 64 + ((((ks) * 4 + fq) ^ swz) * 8)])
#define RD_A(AOFF, mi, ks) \
  (*(const bf16x8*)&lds[(AOFF) + (rAb + (mi) * 16) * 64 + ((((ks) * 4 + fq) ^ swz) * 8)])

#define CLUSTER(mia)                                                            \
  do {                                                                          \
    __builtin_amdgcn_s_setprio(1);                                              \
    _Pragma("unroll") for (int mj = 0; mj < 2; ++mj)                            \
    _Pragma("unroll") for (int nf = 0; nf < 4; ++nf)                            \
    _Pragma("unroll") for (int ks = 0; ks < 2; ++ks)                            \
      acc[(mia) + mj][nf] =                                                     \
          TRANS ? MFMA_BF16(bfr[nf][ks], af[mj][ks], acc[(mia) + mj][nf])       \
                : MFMA_BF16(af[mj][ks], bfr[nf][ks], acc[(mia) + mj][nf]);      \
    __builtin_amdgcn_s_setprio(0);                                              \
  } while (0)

// One K-tile, compile-time dbuf DC, TWO barriers (p1-end, p3-end).
// Stages: A0(t+1)@p0, A1(t+1)@p1 (-> dbuf DC^1), B0(t+2)@p2, B1(t+2)@p3
// (-> dbuf DC). Single wait: vmcnt(4) at p3-end — outstanding there is 12
// {B(t+1)x4 oldest, A0(t+1)x2, A1(t+1)x2, B0(t+2)x2, B1(t+2)x2 newest};
// keeping 4 drains everything tile t+1 reads, leaves {B(t+2)} in flight.
// WAR: B stages (p2/p3) are after the p1-end barrier that follows the last
// B(t) reads (p0); A stages go to the opposite dbuf whose reads finished
// before the previous p3-end barrier.
#define KTILE(DC, t)                                                           \
  {                                                                            \
    constexpr int Boff = (DC) * 32768;                                         \
    constexpr int Aoff = Boff + 16384;                                         \
    constexpr int AoffN = ((DC) ^ 1) * 32768 + 16384;                          \
    bf16x8 bfr[4][2], af[2][2];                                                \
    /* p0: read B(8)+A[0,1](4); stage A0(t+1); c0 */                           \
    _Pragma("unroll") for (int nf = 0; nf < 4; ++nf)                           \
    _Pragma("unroll") for (int ks = 0; ks < 2; ++ks)                           \
      bfr[nf][ks] = RD_B(Boff, nf, ks);                                        \
    _Pragma("unroll") for (int mj = 0; mj < 2; ++mj)                           \
    _Pragma("unroll") for (int ks = 0; ks < 2; ++ks)                           \
      af[mj][ks] = RD_A(Aoff, mj, ks);                                         \
    if ((t) + 1 < NT) STAGE2(Xrow, 0, ((t) + 1) * 64, AoffN);                  \
    CLUSTER(0);                                                                \
    /* p1: read A[2,3]; stage A1(t+1); c2; barrier */                          \
    _Pragma("unroll") for (int mj = 0; mj < 2; ++mj)                           \
    _Pragma("unroll") for (int ks = 0; ks < 2; ++ks)                           \
      af[mj][ks] = RD_A(Aoff, 2 + mj, ks);                                     \
    if ((t) + 1 < NT) STAGE2(Xrow, 128, ((t) + 1) * 64, AoffN + 8192);         \
    CLUSTER(2);                                                                \
    __builtin_amdgcn_s_barrier();                                              \
    /* p2: read A[4,5]; stage B0(t+2); c4 */                                   \
    _Pragma("unroll") for (int mj = 0; mj < 2; ++mj)                           \
    _Pragma("unroll") for (int ks = 0; ks < 2; ++ks)                           \
      af[mj][ks] = RD_A(Aoff, 4 + mj, ks);                                     \
    if ((t) + 2 < NT) STAGE2(Wrow, 0, ((t) + 2) * 64, Boff + 0);               \
    CLUSTER(4);                                                                \
    /* p3: read A[6,7]; stage B1(t+2); c6; vmcnt(4|0); barrier */              \
    _Pragma("unroll") for (int mj = 0; mj < 2; ++mj)                           \
    _Pragma("unroll") for (int ks = 0; ks < 2; ++ks)                           \
      af[mj][ks] = RD_A(Aoff, 6 + mj, ks);                                     \
    if ((t) + 2 < NT) STAGE2(Wrow, 128, ((t) + 2) * 64, Boff + 8192);          \
    CLUSTER(6);                                                                \
    if ((t) + 2 < NT)                                                          \
      asm volatile("s_waitcnt vmcnt(4)" ::: "memory");                         \
    else                                                                       \
      asm volatile("s_waitcnt vmcnt(0)" ::: "memory");                         \
    __builtin_amdgcn_s_barrier();                                              \
  }

  // prologue: t0 {B0,B1,A0,A1} dbuf0; t1 {B0,B1} dbuf1 (A(t1) staged in t0's
  // p0/p1). vmcnt(4) drains B(t0)+A(t0); leaves {B(t1)}=4 = steady invariant.
  STAGE2(Wrow, 0, 0, 0);
  STAGE2(Wrow, 128, 0, 8192);
  STAGE2(Xrow, 0, 0, 16384);
  STAGE2(Xrow, 128, 0, 24576);
  STAGE2(Wrow, 0, 64, 32768);
  STAGE2(Wrow, 128, 64, 32768 + 8192);
  asm volatile("s_waitcnt vmcnt(4)" ::: "memory");
  __builtin_amdgcn_s_barrier();

  for (int tt = 0; tt < NT; tt += 2) {
    KTILE(0, tt);
    KTILE(1, tt + 1);
  }
#undef KTILE
#undef CLUSTER
#undef RD_A
#undef RD_B
#undef STAGE2

  // epilogue: C/D layout col=lane&15, row=(lane>>4)*4+i [m89/m91]
#pragma unroll
  for (int mi = 0; mi < 8; ++mi)
#pragma unroll
    for (int nf = 0; nf < 4; ++nf) {
      int row, col;
      if constexpr (TRANS) {
        row = n0 + wc * 64 + nf * 16 + fq * 4;
        col = m0 + wr * 128 + mi * 16 + fr;
      } else {
        row = m0 + wr * 128 + mi * 16 + fq * 4;
        col = n0 + wc * 64 + nf * 16 + fr;
      }
      if constexpr (OUT_F32) {
        float* yp = (float*)Yv + (size_t)row * kDM + col;
#pragma unroll
        for (int i = 0; i < 4; ++i) yp[(size_t)i * kDM] = acc[mi][nf][i];
      } else {
        u16* yp = (u16*)Yv + (size_t)row * kDM + col;
#pragma unroll
        for (int i = 0; i < 4; ++i) yp[(size_t)i * kDM] = f2bf(acc[mi][nf][i]);
      }
    }
}

// XCD-aware bijective remap (hw flat id -> work id; 8 XCDs, nwg%8==0)
static __device__ __forceinline__ int xcd_swz(int id, int cpx) {
  return (id & 7) * cpx + (id >> 3);
}

__global__ __launch_bounds__(512, 2) void proj_qk256_kernel(const u16* __restrict__ wsb,
                                                            u16* __restrict__ qp,
                                                            u16* __restrict__ kp) {
  __shared__ u16 lds[65536];
  const int z = blockIdx.z;
  const int s = xcd_swz(blockIdx.y * 16 + blockIdx.x, 32);
  const int m0 = (s >> 4) * 256, n0 = (s & 15) * 256;
  gemm256<false, false>(wsb + (size_t)z * kMat, wsb + (size_t)(3 + z) * kMat,
                        z ? kp : qp, lds, m0, n0);
}

__global__ __launch_bounds__(512, 2) void proj_vT256_kernel(const u16* __restrict__ wsb,
                                                            u16* __restrict__ vpT) {
  __shared__ u16 lds[65536];
  const int s = xcd_swz(blockIdx.y * 16 + blockIdx.x, 32);
  gemm256<true, false>(wsb + 2 * kMat, wsb + 5 * kMat, vpT, lds,
                       (s >> 4) * 256, (s & 15) * 256);
}

__global__ __launch_bounds__(512, 2) void out_proj256_kernel(const u16* __restrict__ ctx,
                                                             const u16* __restrict__ Wob,
                                                             float* __restrict__ out) {
  __shared__ u16 lds[65536];
  const int s = xcd_swz(blockIdx.y * 16 + blockIdx.x, 32);
  gemm256<false, true>(ctx, Wob, out, lds, (s >> 4) * 256, (s & 15) * 256);
}

// ---------------------------------------------------------------------------
// FALLBACK path (ws too small): in-GEMM convert staging (R5-verified).
// ---------------------------------------------------------------------------
template <bool A_BF16, bool TRANS, bool OUT_F32>
static __device__ __forceinline__ void gemm_conv(const void* Xv, const float* Wf,
                                                 void* Yv, u16* __restrict__ Als,
                                                 u16* __restrict__ Bls) {
  constexpr int KD = 4096;
  const int tid = threadIdx.x;
  const int lane = tid & 63;
  const int w = tid >> 6;
  const int fr = lane & 15;
  const int fq = lane >> 4;
  const int m0 = blockIdx.y * 128;
  const int n0 = blockIdx.x * 128;

  const int r0 = tid >> 2, cc0 = (tid & 3) * 8;
  const int r1 = r0 + 64;
  const int sr = lane >> 2, sc = (lane & 3) * 8;
  const int u0 = w * 2, u1 = w * 2 + 1;

  const u16* Xb = (const u16*)Xv;
  const float* Xf = (const float*)Xv;

  const int wm = (w >> 1) * 64;
  const int wn = (w & 1) * 64;

  f32x4 acc[4][4] = {};

  for (int kt = 0; kt < KD / 32; ++kt) {
    const int ko = kt * 32;
    if constexpr (A_BF16) {
      gload_lds16(Xb + (size_t)(m0 + u0 * 16 + sr) * KD + ko + sc, &Als[u0 * 512]);
      gload_lds16(Xb + (size_t)(m0 + u1 * 16 + sr) * KD + ko + sc, &Als[u1 * 512]);
    } else {
      const float* p0 = Xf + (size_t)(m0 + r0) * KD + ko + cc0;
      const float* p1 = Xf + (size_t)(m0 + r1) * KD + ko + cc0;
      float4 a0 = *(const float4*)(p0);
      float4 a1 = *(const float4*)(p0 + 4);
      float4 a2 = *(const float4*)(p1);
      float4 a3 = *(const float4*)(p1 + 4);
      *(u16x8*)&Als[r0 * 32 + cc0] = cvt8(a0, a1);
      *(u16x8*)&Als[r1 * 32 + cc0] = cvt8(a2, a3);
    }
    {
      const float* p0 = Wf + (size_t)(n0 + r0) * KD + ko + cc0;
      const float* p1 = Wf + (size_t)(n0 + r1) * KD + ko + cc0;
      float4 b0 = *(const float4*)(p0);
      float4 b1 = *(const float4*)(p0 + 4);
      float4 b2 = *(const float4*)(p1);
      float4 b3 = *(const float4*)(p1 + 4);
      *(u16x8*)&Bls[r0 * 32 + cc0] = cvt8(b0, b1);
      *(u16x8*)&Bls[r1 * 32 + cc0] = cvt8(b2, b3);
    }
    __syncthreads();

    bf16x8 af[4], bfv[4];
#pragma unroll
    for (int i = 0; i < 4; ++i)
      af[i] = *(const bf16x8*)&Als[(wm + i * 16 + fr) * 32 + fq * 8];
#pragma unroll
    for (int i = 0; i < 4; ++i)
      bfv[i] = *(const bf16x8*)&Bls[(wn + i * 16 + fr) * 32 + fq * 8];
#pragma unroll
    for (int a = 0; a < 4; ++a)
#pragma unroll
      for (int bb = 0; bb < 4; ++bb) {
        if constexpr (TRANS)
          acc[a][bb] = MFMA_BF16(bfv[a], af[bb], acc[a][bb]);
        else
          acc[a][bb] = MFMA_BF16(af[a], bfv[bb], acc[a][bb]);
      }
    __syncthreads();
  }

#pragma unroll
  for (int a = 0; a < 4; ++a)
#pragma unroll
    for (int bb = 0; bb < 4; ++bb) {
      const int row = TRANS ? (n0 + wn + a * 16 + fq * 4) : (m0 + wm + a * 16 + fq * 4);
      const int col = TRANS ? (m0 + wm + bb * 16 + fr) : (n0 + wn + bb * 16 + fr);
      if constexpr (OUT_F32) {
        float* yp = (float*)Yv + (size_t)row * kDM + col;
#pragma unroll
        for (int i = 0; i < 4; ++i) yp[(size_t)i * kDM] = acc[a][bb][i];
      } else {
        u16* yp = (u16*)Yv + (size_t)row * kDM + col;
#pragma unroll
        for (int i = 0; i < 4; ++i) yp[(size_t)i * kDM] = f2bf(acc[a][bb][i]);
      }
    }
}

__global__ __launch_bounds__(256) void proj_qk_conv_kernel(
    const float* __restrict__ q, const float* __restrict__ k,
    const float* __restrict__ Wq, const float* __restrict__ Wk,
    u16* __restrict__ qp, u16* __restrict__ kp) {
  __shared__ u16 Als[128 * 32];
  __shared__ u16 Bls[128 * 32];
  const int z = blockIdx.z;
  gemm_conv<false, false, false>(z ? k : q, z ? Wk : Wq, z ? kp : qp, Als, Bls);
}

__global__ __launch_bounds__(256) void proj_vT_conv_kernel(
    const float* __restrict__ v, const float* __restrict__ Wv, u16* __restrict__ vpT) {
  __shared__ u16 Als[128 * 32];
  __shared__ u16 Bls[128 * 32];
  gemm_conv<false, true, false>(v, Wv, vpT, Als, Bls);
}

__global__ __launch_bounds__(256) void out_proj_conv_kernel(const u16* __restrict__ ctx,
                                                            const float* __restrict__ Wo,
                                                            float* __restrict__ out) {
  __shared__ u16 Als[128 * 32];
  __shared__ u16 Bls[128 * 32];
  gemm_conv<true, false, true>(ctx, Wo, out, Als, Bls);
}

// ---------------------------------------------------------------------------
// Flash attention (R9, unchanged): grid (8,64) block 512 = 8 waves.
// Swapped QK^T; conflict-free b64 P-stores; ones-V denom; defer-max;
// reg-staged async K/V prefetch; XCD swizzle.
// ---------------------------------------------------------------------------
__global__ __launch_bounds__(512) void attn_kernel(const u16* __restrict__ qp,
                                                   const u16* __restrict__ kp,
                                                   const u16* __restrict__ vpT,
                                                   u16* __restrict__ ctx) {
  constexpr int KB = 64;
  constexpr int NT = kS / KB;   // 32 tiles
  constexpr int PST = 72;       // P row stride (elems, 16B-aligned rows)
  constexpr float THR = 11.5f;  // defer-max threshold (log2 units ~ e^8)

  __shared__ u16 Kls[KB * 128];        // 16 KB [key][d] chunk-swizzled
  __shared__ u16 Vt[kD * KB];          // 16 KB [d][key] chunk-swizzled
  __shared__ u16 Pls[8][2 * 16 * PST]; // 36 KB per-wave P tiles [q][key]

  const int tid = threadIdx.x, lane = tid & 63, w = tid >> 6;  // w: 0..7
  const int fr = lane & 15, fq = lane >> 4;

  const int wg = blockIdx.y * 8 + blockIdx.x;
  const int o = (wg & 7) * 64 + (wg >> 3);
  const int bh = o >> 3;
  const int b = bh >> 5, h = bh & 31;
  const int q0 = (o & 7) * 256;

  const u16* qbase = qp + ((size_t)b * kS) * kDM + h * kD;
  const u16* kbase = kp + ((size_t)b * kS) * kDM + h * kD;
  const u16* vtbase = vpT + (size_t)(h * kD) * kDM + b * kS;  // row d, stride kDM

  bf16x8 qf[2][4];
#pragma unroll
  for (int rb = 0; rb < 2; ++rb)
#pragma unroll
    for (int kc = 0; kc < 4; ++kc) {
      const u16x8 raw = *(const u16x8*)(qbase +
          (size_t)(q0 + w * 32 + rb * 16 + fr) * kDM + kc * 32 + fq * 8);
      bf16x8 s;
#pragma unroll
      for (int j = 0; j < 8; ++j) s[j] = (short)f2bf(bf2f(raw[j]) * kScaleLog2e);
      qf[rb][kc] = s;
    }

  f32x4 oacc[2][9] = {};
  float mrun[2] = {-1e30f, -1e30f};

  bf16x8 ones;
#pragma unroll
  for (int j = 0; j < 8; ++j) ones[j] = (short)0x3F80;  // bf16 1.0

  const int krl = lane >> 4, kdp = lane & 15;
  const int vdl = lane >> 3, vc = lane & 7;
  const int rk0 = (w * 2 + 0) * 4 + krl;
  const int rk1 = (w * 2 + 1) * 4 + krl;
  const int dv0 = (w * 2 + 0) * 8 + vdl;
  const int dv1 = (w * 2 + 1) * 8 + vdl;
  const u16* kg0 = kbase + (size_t)rk0 * kDM + kdp * 8;
  const u16* kg1 = kbase + (size_t)rk1 * kDM + kdp * 8;
  const u16* vg0 = vtbase + (size_t)dv0 * kDM + vc * 8;
  const u16* vg1 = vtbase + (size_t)dv1 * kDM + vc * 8;
  u16* kl0 = &Kls[rk0 * 128 + ((kdp ^ (rk0 & 7)) * 8)];
  u16* kl1 = &Kls[rk1 * 128 + ((kdp ^ (rk1 & 7)) * 8)];
  u16* vl0 = &Vt[dv0 * KB + ((vc ^ (dv0 & 7)) * 8)];
  u16* vl1 = &Vt[dv1 * KB + ((vc ^ (dv1 & 7)) * 8)];

  u16x8 kr0v, kr1v, vr0v, vr1v;
  kr0v = *(const u16x8*)kg0;
  kr1v = *(const u16x8*)kg1;
  vr0v = *(const u16x8*)vg0;
  vr1v = *(const u16x8*)vg1;
  *(u16x8*)kl0 = kr0v; *(u16x8*)kl1 = kr1v;
  *(u16x8*)vl0 = vr0v; *(u16x8*)vl1 = vr1v;
  __syncthreads();

  for (int kt = 0; kt < NT; ++kt) {
    if (kt + 1 < NT) {
      const size_t ko = (size_t)(kt + 1) * KB;
      kr0v = *(const u16x8*)(kg0 + ko * kDM);
      kr1v = *(const u16x8*)(kg1 + ko * kDM);
      vr0v = *(const u16x8*)(vg0 + ko);
      vr1v = *(const u16x8*)(vg1 + ko);
    }

    // --- QK^T (swapped: mfma(K, Q)) ---
    f32x4 sacc[2][4] = {};
#pragma unroll
    for (int cb = 0; cb < 4; ++cb) {
      const int n = cb * 16 + fr;
      bf16x8 kf[4];
#pragma unroll
      for (int kc = 0; kc < 4; ++kc) {
        const int d0 = kc * 4 + fq;
        kf[kc] = *(const bf16x8*)&Kls[n * 128 + (d0 ^ (n & 7)) * 8];
      }
      __builtin_amdgcn_s_setprio(1);
#pragma unroll
      for (int rb = 0; rb < 2; ++rb)
#pragma unroll
        for (int kc = 0; kc < 4; ++kc)
          sacc[rb][cb] = MFMA_BF16(kf[kc], qf[rb][kc], sacc[rb][cb]);
      __builtin_amdgcn_s_setprio(0);
    }

    // --- online softmax: lane owns row q=fr; keys = cb*16 + fq*4 + i ---
#pragma unroll
    for (int rb = 0; rb < 2; ++rb) {
      float m = sacc[rb][0][0];
#pragma unroll
      for (int cb = 0; cb < 4; ++cb)
#pragma unroll
        for (int i = 0; i < 4; ++i) m = fmaxf(m, sacc[rb][cb][i]);
      m = fmaxf(m, __shfl_xor(m, 16));
      m = fmaxf(m, __shfl_xor(m, 32));

      if (__any(m - mrun[rb] > THR)) {
        const float mnew = fmaxf(mrun[rb], m);
        const float sclS = exp2f(mrun[rb] - mnew);
        mrun[rb] = mnew;
        float scl[4];
#pragma unroll
        for (int i = 0; i < 4; ++i) scl[i] = __shfl(sclS, fq * 4 + i);
#pragma unroll
        for (int db = 0; db < 9; ++db)
#pragma unroll
          for (int i = 0; i < 4; ++i) oacc[rb][db][i] *= scl[i];
      }

#pragma unroll
      for (int cb = 0; cb < 4; ++cb) {
        u16x4 pk;
#pragma unroll
        for (int i = 0; i < 4; ++i)
          pk[i] = nbf(exp2f(sacc[rb][cb][i] - mrun[rb]));
        *(u16x4*)&Pls[w][rb * (16 * PST) + fr * PST + cb * 16 + fq * 4] = pk;
      }
    }

    asm volatile("s_waitcnt lgkmcnt(0)" ::: "memory");

    // --- PV (+ denom via ones-V) ---
    bf16x8 pf[2][2];
#pragma unroll
    for (int rb = 0; rb < 2; ++rb)
#pragma unroll
      for (int kb = 0; kb < 2; ++kb)
        pf[rb][kb] = *(const bf16x8*)&Pls[w][rb * (16 * PST) + fr * PST + kb * 32 + fq * 8];
#pragma unroll
    for (int db = 0; db < 8; ++db) {
      const int d = db * 16 + fr;
      bf16x8 vf0 = *(const bf16x8*)&Vt[d * KB + ((fq ^ (d & 7)) << 3)];
      bf16x8 vf1 = *(const bf16x8*)&Vt[d * KB + (((4 + fq) ^ (d & 7)) << 3)];
      __builtin_amdgcn_s_setprio(1);
#pragma unroll
      for (int rb = 0; rb < 2; ++rb) {
        oacc[rb][db] = MFMA_BF16(pf[rb][0], vf0, oacc[rb][db]);
        oacc[rb][db] = MFMA_BF16(pf[rb][1], vf1, oacc[rb][db]);
      }
      __builtin_amdgcn_s_setprio(0);
    }
    __builtin_amdgcn_s_setprio(1);
#pragma unroll
    for (int rb = 0; rb < 2; ++rb) {
      oacc[rb][8] = MFMA_BF16(pf[rb][0], ones, oacc[rb][8]);
      oacc[rb][8] = MFMA_BF16(pf[rb][1], ones, oacc[rb][8]);
    }
    __builtin_amdgcn_s_setprio(0);

    __syncthreads();
    if (kt + 1 < NT) {
      *(u16x8*)kl0 = kr0v; *(u16x8*)kl1 = kr1v;
      *(u16x8*)vl0 = vr0v; *(u16x8*)vl1 = vr1v;
    }
    __syncthreads();
  }

  u16* cbase = ctx + ((size_t)b * kS) * kDM + h * kD;
#pragma unroll
  for (int rb = 0; rb < 2; ++rb) {
    float inv[4];
#pragma unroll
    for (int i = 0; i < 4; ++i) inv[i] = 1.0f / oacc[rb][8][i];
#pragma unroll
    for (int db = 0; db < 8; ++db)
#pragma unroll
      for (int i = 0; i < 4; ++i) {
        const int row = q0 + w * 32 + rb * 16 + fq * 4 + i;
        const int col = db * 16 + fr;
        cbase[(size_t)row * kDM + col] = nbf(oacc[rb][db][i] * inv[i]);
      }
  }
}

// ---------------------------------------------------------------------------
extern "C" void kernel_launch(void* const* d_in, const int* in_sizes, int n_in,
                              void* d_out, int out_size, void* d_ws, size_t ws_size,
                              hipStream_t stream) {
  const float* q = (const float*)d_in[0];
  const float* k = (const float*)d_in[1];
  const float* v = (const float*)d_in[2];
  const float* Wq = (const float*)d_in[3];
  const float* Wk = (const float*)d_in[4];
  const float* Wv = (const float*)d_in[5];
  const float* Wo = (const float*)d_in[6];
  float* out = (float*)d_out;

  const size_t needFast = 11 * kMat * sizeof(u16);  // 7 bf16 inputs + qp/kp/vpT/ctx

  if (ws_size >= needFast) {
    u16* wsb = (u16*)d_ws;            // [0..6]: qb kb vb Wqb Wkb Wvb Wob
    u16* qp = wsb + 7 * kMat;
    u16* kp = wsb + 8 * kMat;
    u16* vpT = wsb + 9 * kMat;
    u16* ctx = wsb + 10 * kMat;

    cvt_kernel<<<dim3(1024, 7), 256, 0, stream>>>(q, k, v, Wq, Wk, Wv, Wo, wsb);
    proj_qk256_kernel<<<dim3(16, 16, 2), 512, 0, stream>>>(wsb, qp, kp);
    proj_vT256_kernel<<<dim3(16, 16), 512, 0, stream>>>(wsb, vpT);
    attn_kernel<<<dim3(8, 64), 512, 0, stream>>>(qp, kp, vpT, ctx);
    out_proj256_kernel<<<dim3(16, 16), 512, 0, stream>>>(ctx, wsb + 6 * kMat, out);
  } else {
    u16* qp = (u16*)d_ws;
    u16* kp = qp + kMat;
    u16* vpT = kp + kMat;
    u16* ctx = vpT + kMat;

    proj_qk_conv_kernel<<<dim3(32, 32, 2), 256, 0, stream>>>(q, k, Wq, Wk, qp, kp);
    proj_vT_conv_kernel<<<dim3(32, 32), 256, 0, stream>>>(v, Wv, vpT);
    attn_kernel<<<dim3(8, 64), 512, 0, stream>>>(qp, kp, vpT, ctx);
    out_proj_conv_kernel<<<dim3(32, 32, 1), 256, 0, stream>>>(ctx, Wo, out);
  }
}

// Round 17
// 721.642 us; speedup vs baseline: 1.8311x; 1.0046x over previous
//
#include <hip/hip_runtime.h>
#include <hip/hip_bf16.h>
#include <stdint.h>

// ============================================================================
// MultiHeadAttention: y = softmax((xq Wq^T)(xk Wk^T)^T * scale) (xv Wv^T) Wo^T
// B=2, S=2048, H=32, D=128, DM=4096. I/O float32.
// R17: merge proj_qk + proj_vT into ONE kernel (grid (16,16,3); z=0/1 Q/K,
// z=2 V-transposed). 768 blocks = exactly 3 rounds at 1 block/CU: removes a
// grid-drain + launch boundary. GEMM schedule = R16 (2 barriers/K-tile,
// ledger-verified vmcnt(4)). Attn (R9) and cvt unchanged.
// ============================================================================

using u16 = unsigned short;
using u32 = unsigned int;

typedef __attribute__((ext_vector_type(8))) short bf16x8;  // MFMA A/B frag (8 bf16)
typedef __attribute__((ext_vector_type(8))) u16 u16x8;
typedef __attribute__((ext_vector_type(4))) u16 u16x4;
typedef __attribute__((ext_vector_type(4))) float f32x4;   // MFMA C/D frag

#define MFMA_BF16(A, B, C) __builtin_amdgcn_mfma_f32_16x16x32_bf16((A), (B), (C), 0, 0, 0)

static constexpr int kS = 2048, kDM = 4096, kD = 128;
static constexpr size_t kMat = (size_t)4096 * 4096;
// SCALE * log2(e): softmax computed in exp2 domain
static constexpr float kScaleLog2e = 0.08838834764831845f * 1.44269504088896340736f;

static __device__ __forceinline__ void gload_lds16(const u16* g, u16* l) {
  __builtin_amdgcn_global_load_lds((const __attribute__((address_space(1))) void*)g,
                                   (__attribute__((address_space(3))) void*)l, 16, 0, 0);
}

static __device__ __forceinline__ u16 f2bf(float f) {  // RNE f32 -> bf16 bits (sw)
  u32 u = __float_as_uint(f);
  u32 r = u + 0x7FFFu + ((u >> 16) & 1u);
  return (u16)(r >> 16);
}

static __device__ __forceinline__ float bf2f(u16 x) {  // exact bf16 -> f32
  return __uint_as_float((u32)x << 16);
}

static __device__ __forceinline__ u16 nbf(float f) {  // native cast (hw cvt)
  union { __hip_bfloat16 h; u16 u; } cv;
  cv.h = __float2bfloat16(f);
  return cv.u;
}

static __device__ __forceinline__ u16x8 cvt8(float4 a, float4 b) {
  u16x8 r;
  r[0] = f2bf(a.x); r[1] = f2bf(a.y); r[2] = f2bf(a.z); r[3] = f2bf(a.w);
  r[4] = f2bf(b.x); r[5] = f2bf(b.y); r[6] = f2bf(b.z); r[7] = f2bf(b.w);
  return r;
}

// ---------------------------------------------------------------------------
// f32 -> bf16 bulk conversion: 7 matrices of kMat elems. Grid (X, 7).
// ---------------------------------------------------------------------------
__global__ __launch_bounds__(256) void cvt_kernel(
    const float* __restrict__ s0, const float* __restrict__ s1,
    const float* __restrict__ s2, const float* __restrict__ s3,
    const float* __restrict__ s4, const float* __restrict__ s5,
    const float* __restrict__ s6, u16* __restrict__ dst) {
  const int y = blockIdx.y;
  const float* s = (y == 0) ? s0 : (y == 1) ? s1 : (y == 2) ? s2 : (y == 3) ? s3
                  : (y == 4) ? s4 : (y == 5) ? s5 : s6;
  u16* d = dst + (size_t)y * kMat;
  const size_t nchunk = kMat / 8;
  const size_t step = (size_t)gridDim.x * 256;
  for (size_t c = (size_t)blockIdx.x * 256 + threadIdx.x; c < nchunk; c += step) {
    const float* p = s + c * 8;
    float4 a = *(const float4*)p;
    float4 b = *(const float4*)(p + 4);
    *(u16x8*)(d + c * 8) = cvt8(a, b);
  }
}

// ---------------------------------------------------------------------------
// 256x256 GEMM, 2 barriers per K-tile (R16, race-fixed). Y[m][n]=sum X*W^T.
// 512 thr = 8 waves, per-wave 128x64, BK=64, 128KB LDS dbuf, constexpr
// dbuf offsets.
// ---------------------------------------------------------------------------
template <bool TRANS, bool OUT_F32>
static __device__ __forceinline__ void gemm256(const u16* __restrict__ X,
                                               const u16* __restrict__ W,
                                               void* __restrict__ Yv,
                                               u16* __restrict__ lds,
                                               int m0, int n0) {
  constexpr int NT = kDM / 64;
  const int tid = threadIdx.x;
  const int lane = tid & 63;
  const int w = tid >> 6;
  const int fr = lane & 15;
  const int fq = lane >> 4;
  const int wr = w >> 2;  // 0..1  (M half)
  const int wc = w & 3;   // 0..3  (N quarter)

  const int srow = tid >> 3;
  const int scol = ((tid & 7) ^ (srow & 7)) * 8;
  const u16* Xrow = X + (size_t)(m0 + srow) * kDM + scol;
  const u16* Wrow = W + (size_t)(n0 + srow) * kDM + scol;
  const int w512 = w * 512;

  const int rBb = wc * 64 + fr;
  const int rAb = wr * 128 + fr;
  const int swz = fr & 7;

  f32x4 acc[8][4] = {};

#define STAGE2(ROWP, qrow, k0, ldq)                                        \
  do {                                                                     \
    gload_lds16((ROWP) + (size_t)(qrow) * kDM + (k0), &lds[(ldq) + w512]); \
    gload_lds16((ROWP) + (size_t)((qrow) + 64) * kDM + (k0),               \
                &lds[(ldq) + 4096 + w512]);                                \
  } while (0)

#define RD_B(BOFF, nf, ks) \
  (*(const bf16x8*)&lds[(BOFF) + (rBb + (nf) * 16) * 64 + ((((ks) * 4 + fq) ^ swz) * 8)])
#define RD_A(AOFF, mi, ks) \
  (*(const bf16x8*)&lds[(AOFF) + (rAb + (mi) * 16) * 64 + ((((ks) * 4 + fq) ^ swz) * 8)])

#define CLUSTER(mia)                                                            \
  do {                                                                          \
    __builtin_amdgcn_s_setprio(1);                                              \
    _Pragma("unroll") for (int mj = 0; mj < 2; ++mj)                            \
    _Pragma("unroll") for (int nf = 0; nf < 4; ++nf)                            \
    _Pragma("unroll") for (int ks = 0; ks < 2; ++ks)                            \
      acc[(mia) + mj][nf] =                                                     \
          TRANS ? MFMA_BF16(bfr[nf][ks], af[mj][ks], acc[(mia) + mj][nf])       \
                : MFMA_BF16(af[mj][ks], bfr[nf][ks], acc[(mia) + mj][nf]);      \
    __builtin_amdgcn_s_setprio(0);                                              \
  } while (0)

// One K-tile, compile-time dbuf DC, TWO barriers (p1-end, p3-end).
// Stages: A0(t+1)@p0, A1(t+1)@p1 (-> dbuf DC^1), B0(t+2)@p2, B1(t+2)@p3
// (-> dbuf DC). vmcnt(4) at p3-end: outstanding=12, keeping 4 drains all
// of tile t+1's data, leaves {B(t+2)} in flight.
#define KTILE(DC, t)                                                           \
  {                                                                            \
    constexpr int Boff = (DC) * 32768;                                         \
    constexpr int Aoff = Boff + 16384;                                         \
    constexpr int AoffN = ((DC) ^ 1) * 32768 + 16384;                          \
    bf16x8 bfr[4][2], af[2][2];                                                \
    /* p0: read B(8)+A[0,1](4); stage A0(t+1); c0 */                           \
    _Pragma("unroll") for (int nf = 0; nf < 4; ++nf)                           \
    _Pragma("unroll") for (int ks = 0; ks < 2; ++ks)                           \
      bfr[nf][ks] = RD_B(Boff, nf, ks);                                        \
    _Pragma("unroll") for (int mj = 0; mj < 2; ++mj)                           \
    _Pragma("unroll") for (int ks = 0; ks < 2; ++ks)                           \
      af[mj][ks] = RD_A(Aoff, mj, ks);                                         \
    if ((t) + 1 < NT) STAGE2(Xrow, 0, ((t) + 1) * 64, AoffN);                  \
    CLUSTER(0);                                                                \
    /* p1: read A[2,3]; stage A1(t+1); c2; barrier */                          \
    _Pragma("unroll") for (int mj = 0; mj < 2; ++mj)                           \
    _Pragma("unroll") for (int ks = 0; ks < 2; ++ks)                           \
      af[mj][ks] = RD_A(Aoff, 2 + mj, ks);                                     \
    if ((t) + 1 < NT) STAGE2(Xrow, 128, ((t) + 1) * 64, AoffN + 8192);         \
    CLUSTER(2);                                                                \
    __builtin_amdgcn_s_barrier();                                              \
    /* p2: read A[4,5]; stage B0(t+2); c4 */                                   \
    _Pragma("unroll") for (int mj = 0; mj < 2; ++mj)                           \
    _Pragma("unroll") for (int ks = 0; ks < 2; ++ks)                           \
      af[mj][ks] = RD_A(Aoff, 4 + mj, ks);                                     \
    if ((t) + 2 < NT) STAGE2(Wrow, 0, ((t) + 2) * 64, Boff + 0);               \
    CLUSTER(4);                                                                \
    /* p3: read A[6,7]; stage B1(t+2); c6; vmcnt(4|0); barrier */              \
    _Pragma("unroll") for (int mj = 0; mj < 2; ++mj)                           \
    _Pragma("unroll") for (int ks = 0; ks < 2; ++ks)                           \
      af[mj][ks] = RD_A(Aoff, 6 + mj, ks);                                     \
    if ((t) + 2 < NT) STAGE2(Wrow, 128, ((t) + 2) * 64, Boff + 8192);          \
    CLUSTER(6);                                                                \
    if ((t) + 2 < NT)                                                          \
      asm volatile("s_waitcnt vmcnt(4)" ::: "memory");                         \
    else                                                                       \
      asm volatile("s_waitcnt vmcnt(0)" ::: "memory");                         \
    __builtin_amdgcn_s_barrier();                                              \
  }

  // prologue: t0 {B0,B1,A0,A1} dbuf0; t1 {B0,B1} dbuf1 (A(t1) staged in t0's
  // p0/p1). vmcnt(4) drains B(t0)+A(t0); leaves {B(t1)}=4 = steady invariant.
  STAGE2(Wrow, 0, 0, 0);
  STAGE2(Wrow, 128, 0, 8192);
  STAGE2(Xrow, 0, 0, 16384);
  STAGE2(Xrow, 128, 0, 24576);
  STAGE2(Wrow, 0, 64, 32768);
  STAGE2(Wrow, 128, 64, 32768 + 8192);
  asm volatile("s_waitcnt vmcnt(4)" ::: "memory");
  __builtin_amdgcn_s_barrier();

  for (int tt = 0; tt < NT; tt += 2) {
    KTILE(0, tt);
    KTILE(1, tt + 1);
  }
#undef KTILE
#undef CLUSTER
#undef RD_A
#undef RD_B
#undef STAGE2

  // epilogue: C/D layout col=lane&15, row=(lane>>4)*4+i [m89/m91]
#pragma unroll
  for (int mi = 0; mi < 8; ++mi)
#pragma unroll
    for (int nf = 0; nf < 4; ++nf) {
      int row, col;
      if constexpr (TRANS) {
        row = n0 + wc * 64 + nf * 16 + fq * 4;
        col = m0 + wr * 128 + mi * 16 + fr;
      } else {
        row = m0 + wr * 128 + mi * 16 + fq * 4;
        col = n0 + wc * 64 + nf * 16 + fr;
      }
      if constexpr (OUT_F32) {
        float* yp = (float*)Yv + (size_t)row * kDM + col;
#pragma unroll
        for (int i = 0; i < 4; ++i) yp[(size_t)i * kDM] = acc[mi][nf][i];
      } else {
        u16* yp = (u16*)Yv + (size_t)row * kDM + col;
#pragma unroll
        for (int i = 0; i < 4; ++i) yp[(size_t)i * kDM] = f2bf(acc[mi][nf][i]);
      }
    }
}

// XCD-aware bijective remap (hw flat id -> work id; 8 XCDs, nwg%8==0)
static __device__ __forceinline__ int xcd_swz(int id, int cpx) {
  return (id & 7) * cpx + (id >> 3);
}

// Merged projections: z=0 Q, z=1 K (straight), z=2 V (transposed output).
// 768 blocks = exactly 3 rounds at 1 block/CU; z-rounds are dispatch-ordered
// so each round works on one GEMM's L2 set.
__global__ __launch_bounds__(512, 2) void proj_all256_kernel(const u16* __restrict__ wsb,
                                                             u16* __restrict__ qp,
                                                             u16* __restrict__ kp,
                                                             u16* __restrict__ vpT) {
  __shared__ u16 lds[65536];
  const int z = blockIdx.z;
  const int s = xcd_swz(blockIdx.y * 16 + blockIdx.x, 32);
  const int m0 = (s >> 4) * 256, n0 = (s & 15) * 256;
  if (z == 0)
    gemm256<false, false>(wsb, wsb + 3 * kMat, qp, lds, m0, n0);
  else if (z == 1)
    gemm256<false, false>(wsb + kMat, wsb + 4 * kMat, kp, lds, m0, n0);
  else
    gemm256<true, false>(wsb + 2 * kMat, wsb + 5 * kMat, vpT, lds, m0, n0);
}

__global__ __launch_bounds__(512, 2) void out_proj256_kernel(const u16* __restrict__ ctx,
                                                             const u16* __restrict__ Wob,
                                                             float* __restrict__ out) {
  __shared__ u16 lds[65536];
  const int s = xcd_swz(blockIdx.y * 16 + blockIdx.x, 32);
  gemm256<false, true>(ctx, Wob, out, lds, (s >> 4) * 256, (s & 15) * 256);
}

// ---------------------------------------------------------------------------
// FALLBACK path (ws too small): in-GEMM convert staging (R5-verified).
// ---------------------------------------------------------------------------
template <bool A_BF16, bool TRANS, bool OUT_F32>
static __device__ __forceinline__ void gemm_conv(const void* Xv, const float* Wf,
                                                 void* Yv, u16* __restrict__ Als,
                                                 u16* __restrict__ Bls) {
  constexpr int KD = 4096;
  const int tid = threadIdx.x;
  const int lane = tid & 63;
  const int w = tid >> 6;
  const int fr = lane & 15;
  const int fq = lane >> 4;
  const int m0 = blockIdx.y * 128;
  const int n0 = blockIdx.x * 128;

  const int r0 = tid >> 2, cc0 = (tid & 3) * 8;
  const int r1 = r0 + 64;
  const int sr = lane >> 2, sc = (lane & 3) * 8;
  const int u0 = w * 2, u1 = w * 2 + 1;

  const u16* Xb = (const u16*)Xv;
  const float* Xf = (const float*)Xv;

  const int wm = (w >> 1) * 64;
  const int wn = (w & 1) * 64;

  f32x4 acc[4][4] = {};

  for (int kt = 0; kt < KD / 32; ++kt) {
    const int ko = kt * 32;
    if constexpr (A_BF16) {
      gload_lds16(Xb + (size_t)(m0 + u0 * 16 + sr) * KD + ko + sc, &Als[u0 * 512]);
      gload_lds16(Xb + (size_t)(m0 + u1 * 16 + sr) * KD + ko + sc, &Als[u1 * 512]);
    } else {
      const float* p0 = Xf + (size_t)(m0 + r0) * KD + ko + cc0;
      const float* p1 = Xf + (size_t)(m0 + r1) * KD + ko + cc0;
      float4 a0 = *(const float4*)(p0);
      float4 a1 = *(const float4*)(p0 + 4);
      float4 a2 = *(const float4*)(p1);
      float4 a3 = *(const float4*)(p1 + 4);
      *(u16x8*)&Als[r0 * 32 + cc0] = cvt8(a0, a1);
      *(u16x8*)&Als[r1 * 32 + cc0] = cvt8(a2, a3);
    }
    {
      const float* p0 = Wf + (size_t)(n0 + r0) * KD + ko + cc0;
      const float* p1 = Wf + (size_t)(n0 + r1) * KD + ko + cc0;
      float4 b0 = *(const float4*)(p0);
      float4 b1 = *(const float4*)(p0 + 4);
      float4 b2 = *(const float4*)(p1);
      float4 b3 = *(const float4*)(p1 + 4);
      *(u16x8*)&Bls[r0 * 32 + cc0] = cvt8(b0, b1);
      *(u16x8*)&Bls[r1 * 32 + cc0] = cvt8(b2, b3);
    }
    __syncthreads();

    bf16x8 af[4], bfv[4];
#pragma unroll
    for (int i = 0; i < 4; ++i)
      af[i] = *(const bf16x8*)&Als[(wm + i * 16 + fr) * 32 + fq * 8];
#pragma unroll
    for (int i = 0; i < 4; ++i)
      bfv[i] = *(const bf16x8*)&Bls[(wn + i * 16 + fr) * 32 + fq * 8];
#pragma unroll
    for (int a = 0; a < 4; ++a)
#pragma unroll
      for (int bb = 0; bb < 4; ++bb) {
        if constexpr (TRANS)
          acc[a][bb] = MFMA_BF16(bfv[a], af[bb], acc[a][bb]);
        else
          acc[a][bb] = MFMA_BF16(af[a], bfv[bb], acc[a][bb]);
      }
    __syncthreads();
  }

#pragma unroll
  for (int a = 0; a < 4; ++a)
#pragma unroll
    for (int bb = 0; bb < 4; ++bb) {
      const int row = TRANS ? (n0 + wn + a * 16 + fq * 4) : (m0 + wm + a * 16 + fq * 4);
      const int col = TRANS ? (m0 + wm + bb * 16 + fr) : (n0 + wn + bb * 16 + fr);
      if constexpr (OUT_F32) {
        float* yp = (float*)Yv + (size_t)row * kDM + col;
#pragma unroll
        for (int i = 0; i < 4; ++i) yp[(size_t)i * kDM] = acc[a][bb][i];
      } else {
        u16* yp = (u16*)Yv + (size_t)row * kDM + col;
#pragma unroll
        for (int i = 0; i < 4; ++i) yp[(size_t)i * kDM] = f2bf(acc[a][bb][i]);
      }
    }
}

__global__ __launch_bounds__(256) void proj_qk_conv_kernel(
    const float* __restrict__ q, const float* __restrict__ k,
    const float* __restrict__ Wq, const float* __restrict__ Wk,
    u16* __restrict__ qp, u16* __restrict__ kp) {
  __shared__ u16 Als[128 * 32];
  __shared__ u16 Bls[128 * 32];
  const int z = blockIdx.z;
  gemm_conv<false, false, false>(z ? k : q, z ? Wk : Wq, z ? kp : qp, Als, Bls);
}

__global__ __launch_bounds__(256) void proj_vT_conv_kernel(
    const float* __restrict__ v, const float* __restrict__ Wv, u16* __restrict__ vpT) {
  __shared__ u16 Als[128 * 32];
  __shared__ u16 Bls[128 * 32];
  gemm_conv<false, true, false>(v, Wv, vpT, Als, Bls);
}

__global__ __launch_bounds__(256) void out_proj_conv_kernel(const u16* __restrict__ ctx,
                                                            const float* __restrict__ Wo,
                                                            float* __restrict__ out) {
  __shared__ u16 Als[128 * 32];
  __shared__ u16 Bls[128 * 32];
  gemm_conv<true, false, true>(ctx, Wo, out, Als, Bls);
}

// ---------------------------------------------------------------------------
// Flash attention (R9, unchanged): grid (8,64) block 512 = 8 waves.
// Swapped QK^T; conflict-free b64 P-stores; ones-V denom; defer-max;
// reg-staged async K/V prefetch; XCD swizzle.
// ---------------------------------------------------------------------------
__global__ __launch_bounds__(512) void attn_kernel(const u16* __restrict__ qp,
                                                   const u16* __restrict__ kp,
                                                   const u16* __restrict__ vpT,
                                                   u16* __restrict__ ctx) {
  constexpr int KB = 64;
  constexpr int NT = kS / KB;   // 32 tiles
  constexpr int PST = 72;       // P row stride (elems, 16B-aligned rows)
  constexpr float THR = 11.5f;  // defer-max threshold (log2 units ~ e^8)

  __shared__ u16 Kls[KB * 128];        // 16 KB [key][d] chunk-swizzled
  __shared__ u16 Vt[kD * KB];          // 16 KB [d][key] chunk-swizzled
  __shared__ u16 Pls[8][2 * 16 * PST]; // 36 KB per-wave P tiles [q][key]

  const int tid = threadIdx.x, lane = tid & 63, w = tid >> 6;  // w: 0..7
  const int fr = lane & 15, fq = lane >> 4;

  const int wg = blockIdx.y * 8 + blockIdx.x;
  const int o = (wg & 7) * 64 + (wg >> 3);
  const int bh = o >> 3;
  const int b = bh >> 5, h = bh & 31;
  const int q0 = (o & 7) * 256;

  const u16* qbase = qp + ((size_t)b * kS) * kDM + h * kD;
  const u16* kbase = kp + ((size_t)b * kS) * kDM + h * kD;
  const u16* vtbase = vpT + (size_t)(h * kD) * kDM + b * kS;  // row d, stride kDM

  bf16x8 qf[2][4];
#pragma unroll
  for (int rb = 0; rb < 2; ++rb)
#pragma unroll
    for (int kc = 0; kc < 4; ++kc) {
      const u16x8 raw = *(const u16x8*)(qbase +
          (size_t)(q0 + w * 32 + rb * 16 + fr) * kDM + kc * 32 + fq * 8);
      bf16x8 s;
#pragma unroll
      for (int j = 0; j < 8; ++j) s[j] = (short)f2bf(bf2f(raw[j]) * kScaleLog2e);
      qf[rb][kc] = s;
    }

  f32x4 oacc[2][9] = {};
  float mrun[2] = {-1e30f, -1e30f};

  bf16x8 ones;
#pragma unroll
  for (int j = 0; j < 8; ++j) ones[j] = (short)0x3F80;  // bf16 1.0

  const int krl = lane >> 4, kdp = lane & 15;
  const int vdl = lane >> 3, vc = lane & 7;
  const int rk0 = (w * 2 + 0) * 4 + krl;
  const int rk1 = (w * 2 + 1) * 4 + krl;
  const int dv0 = (w * 2 + 0) * 8 + vdl;
  const int dv1 = (w * 2 + 1) * 8 + vdl;
  const u16* kg0 = kbase + (size_t)rk0 * kDM + kdp * 8;
  const u16* kg1 = kbase + (size_t)rk1 * kDM + kdp * 8;
  const u16* vg0 = vtbase + (size_t)dv0 * kDM + vc * 8;
  const u16* vg1 = vtbase + (size_t)dv1 * kDM + vc * 8;
  u16* kl0 = &Kls[rk0 * 128 + ((kdp ^ (rk0 & 7)) * 8)];
  u16* kl1 = &Kls[rk1 * 128 + ((kdp ^ (rk1 & 7)) * 8)];
  u16* vl0 = &Vt[dv0 * KB + ((vc ^ (dv0 & 7)) * 8)];
  u16* vl1 = &Vt[dv1 * KB + ((vc ^ (dv1 & 7)) * 8)];

  u16x8 kr0v, kr1v, vr0v, vr1v;
  kr0v = *(const u16x8*)kg0;
  kr1v = *(const u16x8*)kg1;
  vr0v = *(const u16x8*)vg0;
  vr1v = *(const u16x8*)vg1;
  *(u16x8*)kl0 = kr0v; *(u16x8*)kl1 = kr1v;
  *(u16x8*)vl0 = vr0v; *(u16x8*)vl1 = vr1v;
  __syncthreads();

  for (int kt = 0; kt < NT; ++kt) {
    if (kt + 1 < NT) {
      const size_t ko = (size_t)(kt + 1) * KB;
      kr0v = *(const u16x8*)(kg0 + ko * kDM);
      kr1v = *(const u16x8*)(kg1 + ko * kDM);
      vr0v = *(const u16x8*)(vg0 + ko);
      vr1v = *(const u16x8*)(vg1 + ko);
    }

    // --- QK^T (swapped: mfma(K, Q)) ---
    f32x4 sacc[2][4] = {};
#pragma unroll
    for (int cb = 0; cb < 4; ++cb) {
      const int n = cb * 16 + fr;
      bf16x8 kf[4];
#pragma unroll
      for (int kc = 0; kc < 4; ++kc) {
        const int d0 = kc * 4 + fq;
        kf[kc] = *(const bf16x8*)&Kls[n * 128 + (d0 ^ (n & 7)) * 8];
      }
      __builtin_amdgcn_s_setprio(1);
#pragma unroll
      for (int rb = 0; rb < 2; ++rb)
#pragma unroll
        for (int kc = 0; kc < 4; ++kc)
          sacc[rb][cb] = MFMA_BF16(kf[kc], qf[rb][kc], sacc[rb][cb]);
      __builtin_amdgcn_s_setprio(0);
    }

    // --- online softmax: lane owns row q=fr; keys = cb*16 + fq*4 + i ---
#pragma unroll
    for (int rb = 0; rb < 2; ++rb) {
      float m = sacc[rb][0][0];
#pragma unroll
      for (int cb = 0; cb < 4; ++cb)
#pragma unroll
        for (int i = 0; i < 4; ++i) m = fmaxf(m, sacc[rb][cb][i]);
      m = fmaxf(m, __shfl_xor(m, 16));
      m = fmaxf(m, __shfl_xor(m, 32));

      if (__any(m - mrun[rb] > THR)) {
        const float mnew = fmaxf(mrun[rb], m);
        const float sclS = exp2f(mrun[rb] - mnew);
        mrun[rb] = mnew;
        float scl[4];
#pragma unroll
        for (int i = 0; i < 4; ++i) scl[i] = __shfl(sclS, fq * 4 + i);
#pragma unroll
        for (int db = 0; db < 9; ++db)
#pragma unroll
          for (int i = 0; i < 4; ++i) oacc[rb][db][i] *= scl[i];
      }

#pragma unroll
      for (int cb = 0; cb < 4; ++cb) {
        u16x4 pk;
#pragma unroll
        for (int i = 0; i < 4; ++i)
          pk[i] = nbf(exp2f(sacc[rb][cb][i] - mrun[rb]));
        *(u16x4*)&Pls[w][rb * (16 * PST) + fr * PST + cb * 16 + fq * 4] = pk;
      }
    }

    asm volatile("s_waitcnt lgkmcnt(0)" ::: "memory");

    // --- PV (+ denom via ones-V) ---
    bf16x8 pf[2][2];
#pragma unroll
    for (int rb = 0; rb < 2; ++rb)
#pragma unroll
      for (int kb = 0; kb < 2; ++kb)
        pf[rb][kb] = *(const bf16x8*)&Pls[w][rb * (16 * PST) + fr * PST + kb * 32 + fq * 8];
#pragma unroll
    for (int db = 0; db < 8; ++db) {
      const int d = db * 16 + fr;
      bf16x8 vf0 = *(const bf16x8*)&Vt[d * KB + ((fq ^ (d & 7)) << 3)];
      bf16x8 vf1 = *(const bf16x8*)&Vt[d * KB + (((4 + fq) ^ (d & 7)) << 3)];
      __builtin_amdgcn_s_setprio(1);
#pragma unroll
      for (int rb = 0; rb < 2; ++rb) {
        oacc[rb][db] = MFMA_BF16(pf[rb][0], vf0, oacc[rb][db]);
        oacc[rb][db] = MFMA_BF16(pf[rb][1], vf1, oacc[rb][db]);
      }
      __builtin_amdgcn_s_setprio(0);
    }
    __builtin_amdgcn_s_setprio(1);
#pragma unroll
    for (int rb = 0; rb < 2; ++rb) {
      oacc[rb][8] = MFMA_BF16(pf[rb][0], ones, oacc[rb][8]);
      oacc[rb][8] = MFMA_BF16(pf[rb][1], ones, oacc[rb][8]);
    }
    __builtin_amdgcn_s_setprio(0);

    __syncthreads();
    if (kt + 1 < NT) {
      *(u16x8*)kl0 = kr0v; *(u16x8*)kl1 = kr1v;
      *(u16x8*)vl0 = vr0v; *(u16x8*)vl1 = vr1v;
    }
    __syncthreads();
  }

  u16* cbase = ctx + ((size_t)b * kS) * kDM + h * kD;
#pragma unroll
  for (int rb = 0; rb < 2; ++rb) {
    float inv[4];
#pragma unroll
    for (int i = 0; i < 4; ++i) inv[i] = 1.0f / oacc[rb][8][i];
#pragma unroll
    for (int db = 0; db < 8; ++db)
#pragma unroll
      for (int i = 0; i < 4; ++i) {
        const int row = q0 + w * 32 + rb * 16 + fq * 4 + i;
        const int col = db * 16 + fr;
        cbase[(size_t)row * kDM + col] = nbf(oacc[rb][db][i] * inv[i]);
      }
  }
}

// ---------------------------------------------------------------------------
extern "C" void kernel_launch(void* const* d_in, const int* in_sizes, int n_in,
                              void* d_out, int out_size, void* d_ws, size_t ws_size,
                              hipStream_t stream) {
  const float* q = (const float*)d_in[0];
  const float* k = (const float*)d_in[1];
  const float* v = (const float*)d_in[2];
  const float* Wq = (const float*)d_in[3];
  const float* Wk = (const float*)d_in[4];
  const float* Wv = (const float*)d_in[5];
  const float* Wo = (const float*)d_in[6];
  float* out = (float*)d_out;

  const size_t needFast = 11 * kMat * sizeof(u16);  // 7 bf16 inputs + qp/kp/vpT/ctx

  if (ws_size >= needFast) {
    u16* wsb = (u16*)d_ws;            // [0..6]: qb kb vb Wqb Wkb Wvb Wob
    u16* qp = wsb + 7 * kMat;
    u16* kp = wsb + 8 * kMat;
    u16* vpT = wsb + 9 * kMat;
    u16* ctx = wsb + 10 * kMat;

    cvt_kernel<<<dim3(1024, 7), 256, 0, stream>>>(q, k, v, Wq, Wk, Wv, Wo, wsb);
    proj_all256_kernel<<<dim3(16, 16, 3), 512, 0, stream>>>(wsb, qp, kp, vpT);
    attn_kernel<<<dim3(8, 64), 512, 0, stream>>>(qp, kp, vpT, ctx);
    out_proj256_kernel<<<dim3(16, 16), 512, 0, stream>>>(ctx, wsb + 6 * kMat, out);
  } else {
    u16* qp = (u16*)d_ws;
    u16* kp = qp + kMat;
    u16* vpT = kp + kMat;
    u16* ctx = vpT + kMat;

    proj_qk_conv_kernel<<<dim3(32, 32, 2), 256, 0, stream>>>(q, k, Wq, Wk, qp, kp);
    proj_vT_conv_kernel<<<dim3(32, 32), 256, 0, stream>>>(v, Wv, vpT);
    attn_kernel<<<dim3(8, 64), 512, 0, stream>>>(qp, kp, vpT, ctx);
    out_proj_conv_kernel<<<dim3(32, 32, 1), 256, 0, stream>>>(ctx, Wo, out);
  }
}

// Round 18
// 719.423 us; speedup vs baseline: 1.8368x; 1.0031x over previous
//
#include <hip/hip_runtime.h>
#include <hip/hip_bf16.h>
#include <stdint.h>

// ============================================================================
// MultiHeadAttention: y = softmax((xq Wq^T)(xk Wk^T)^T * scale) (xv Wv^T) Wo^T
// B=2, S=2048, H=32, D=128, DM=4096. I/O float32.
// R18: attn micro-op — single setprio bracket around all of QK^T and around
// PV+denom (was 17 toggle pairs/tile/wave), denom MFMAs folded into PV tail.
// GEMMs (R16 2-barrier schedule, R17 merged projections) and cvt unchanged.
// ============================================================================

using u16 = unsigned short;
using u32 = unsigned int;

typedef __attribute__((ext_vector_type(8))) short bf16x8;  // MFMA A/B frag (8 bf16)
typedef __attribute__((ext_vector_type(8))) u16 u16x8;
typedef __attribute__((ext_vector_type(4))) u16 u16x4;
typedef __attribute__((ext_vector_type(4))) float f32x4;   // MFMA C/D frag

#define MFMA_BF16(A, B, C) __builtin_amdgcn_mfma_f32_16x16x32_bf16((A), (B), (C), 0, 0, 0)

static constexpr int kS = 2048, kDM = 4096, kD = 128;
static constexpr size_t kMat = (size_t)4096 * 4096;
// SCALE * log2(e): softmax computed in exp2 domain
static constexpr float kScaleLog2e = 0.08838834764831845f * 1.44269504088896340736f;

static __device__ __forceinline__ void gload_lds16(const u16* g, u16* l) {
  __builtin_amdgcn_global_load_lds((const __attribute__((address_space(1))) void*)g,
                                   (__attribute__((address_space(3))) void*)l, 16, 0, 0);
}

static __device__ __forceinline__ u16 f2bf(float f) {  // RNE f32 -> bf16 bits (sw)
  u32 u = __float_as_uint(f);
  u32 r = u + 0x7FFFu + ((u >> 16) & 1u);
  return (u16)(r >> 16);
}

static __device__ __forceinline__ float bf2f(u16 x) {  // exact bf16 -> f32
  return __uint_as_float((u32)x << 16);
}

static __device__ __forceinline__ u16 nbf(float f) {  // native cast (hw cvt)
  union { __hip_bfloat16 h; u16 u; } cv;
  cv.h = __float2bfloat16(f);
  return cv.u;
}

static __device__ __forceinline__ u16x8 cvt8(float4 a, float4 b) {
  u16x8 r;
  r[0] = f2bf(a.x); r[1] = f2bf(a.y); r[2] = f2bf(a.z); r[3] = f2bf(a.w);
  r[4] = f2bf(b.x); r[5] = f2bf(b.y); r[6] = f2bf(b.z); r[7] = f2bf(b.w);
  return r;
}

// ---------------------------------------------------------------------------
// f32 -> bf16 bulk conversion: 7 matrices of kMat elems. Grid (X, 7).
// ---------------------------------------------------------------------------
__global__ __launch_bounds__(256) void cvt_kernel(
    const float* __restrict__ s0, const float* __restrict__ s1,
    const float* __restrict__ s2, const float* __restrict__ s3,
    const float* __restrict__ s4, const float* __restrict__ s5,
    const float* __restrict__ s6, u16* __restrict__ dst) {
  const int y = blockIdx.y;
  const float* s = (y == 0) ? s0 : (y == 1) ? s1 : (y == 2) ? s2 : (y == 3) ? s3
                  : (y == 4) ? s4 : (y == 5) ? s5 : s6;
  u16* d = dst + (size_t)y * kMat;
  const size_t nchunk = kMat / 8;
  const size_t step = (size_t)gridDim.x * 256;
  for (size_t c = (size_t)blockIdx.x * 256 + threadIdx.x; c < nchunk; c += step) {
    const float* p = s + c * 8;
    float4 a = *(const float4*)p;
    float4 b = *(const float4*)(p + 4);
    *(u16x8*)(d + c * 8) = cvt8(a, b);
  }
}

// ---------------------------------------------------------------------------
// 256x256 GEMM, 2 barriers per K-tile (R16, race-fixed). Y[m][n]=sum X*W^T.
// 512 thr = 8 waves, per-wave 128x64, BK=64, 128KB LDS dbuf, constexpr
// dbuf offsets.
// ---------------------------------------------------------------------------
template <bool TRANS, bool OUT_F32>
static __device__ __forceinline__ void gemm256(const u16* __restrict__ X,
                                               const u16* __restrict__ W,
                                               void* __restrict__ Yv,
                                               u16* __restrict__ lds,
                                               int m0, int n0) {
  constexpr int NT = kDM / 64;
  const int tid = threadIdx.x;
  const int lane = tid & 63;
  const int w = tid >> 6;
  const int fr = lane & 15;
  const int fq = lane >> 4;
  const int wr = w >> 2;  // 0..1  (M half)
  const int wc = w & 3;   // 0..3  (N quarter)

  const int srow = tid >> 3;
  const int scol = ((tid & 7) ^ (srow & 7)) * 8;
  const u16* Xrow = X + (size_t)(m0 + srow) * kDM + scol;
  const u16* Wrow = W + (size_t)(n0 + srow) * kDM + scol;
  const int w512 = w * 512;

  const int rBb = wc * 64 + fr;
  const int rAb = wr * 128 + fr;
  const int swz = fr & 7;

  f32x4 acc[8][4] = {};

#define STAGE2(ROWP, qrow, k0, ldq)                                        \
  do {                                                                     \
    gload_lds16((ROWP) + (size_t)(qrow) * kDM + (k0), &lds[(ldq) + w512]); \
    gload_lds16((ROWP) + (size_t)((qrow) + 64) * kDM + (k0),               \
                &lds[(ldq) + 4096 + w512]);                                \
  } while (0)

#define RD_B(BOFF, nf, ks) \
  (*(const bf16x8*)&lds[(BOFF) + (rBb + (nf) * 16) * 64 + ((((ks) * 4 + fq) ^ swz) * 8)])
#define RD_A(AOFF, mi, ks) \
  (*(const bf16x8*)&lds[(AOFF) + (rAb + (mi) * 16) * 64 + ((((ks) * 4 + fq) ^ swz) * 8)])

#define CLUSTER(mia)                                                            \
  do {                                                                          \
    __builtin_amdgcn_s_setprio(1);                                              \
    _Pragma("unroll") for (int mj = 0; mj < 2; ++mj)                            \
    _Pragma("unroll") for (int nf = 0; nf < 4; ++nf)                            \
    _Pragma("unroll") for (int ks = 0; ks < 2; ++ks)                            \
      acc[(mia) + mj][nf] =                                                     \
          TRANS ? MFMA_BF16(bfr[nf][ks], af[mj][ks], acc[(mia) + mj][nf])       \
                : MFMA_BF16(af[mj][ks], bfr[nf][ks], acc[(mia) + mj][nf]);      \
    __builtin_amdgcn_s_setprio(0);                                              \
  } while (0)

// One K-tile, compile-time dbuf DC, TWO barriers (p1-end, p3-end).
// Stages: A0(t+1)@p0, A1(t+1)@p1 (-> dbuf DC^1), B0(t+2)@p2, B1(t+2)@p3
// (-> dbuf DC). vmcnt(4) at p3-end: outstanding=12, keeping 4 drains all
// of tile t+1's data, leaves {B(t+2)} in flight.
#define KTILE(DC, t)                                                           \
  {                                                                            \
    constexpr int Boff = (DC) * 32768;                                         \
    constexpr int Aoff = Boff + 16384;                                         \
    constexpr int AoffN = ((DC) ^ 1) * 32768 + 16384;                          \
    bf16x8 bfr[4][2], af[2][2];                                                \
    /* p0: read B(8)+A[0,1](4); stage A0(t+1); c0 */                           \
    _Pragma("unroll") for (int nf = 0; nf < 4; ++nf)                           \
    _Pragma("unroll") for (int ks = 0; ks < 2; ++ks)                           \
      bfr[nf][ks] = RD_B(Boff, nf, ks);                                        \
    _Pragma("unroll") for (int mj = 0; mj < 2; ++mj)                           \
    _Pragma("unroll") for (int ks = 0; ks < 2; ++ks)                           \
      af[mj][ks] = RD_A(Aoff, mj, ks);                                         \
    if ((t) + 1 < NT) STAGE2(Xrow, 0, ((t) + 1) * 64, AoffN);                  \
    CLUSTER(0);                                                                \
    /* p1: read A[2,3]; stage A1(t+1); c2; barrier */                          \
    _Pragma("unroll") for (int mj = 0; mj < 2; ++mj)                           \
    _Pragma("unroll") for (int ks = 0; ks < 2; ++ks)                           \
      af[mj][ks] = RD_A(Aoff, 2 + mj, ks);                                     \
    if ((t) + 1 < NT) STAGE2(Xrow, 128, ((t) + 1) * 64, AoffN + 8192);         \
    CLUSTER(2);                                                                \
    __builtin_amdgcn_s_barrier();                                              \
    /* p2: read A[4,5]; stage B0(t+2); c4 */                                   \
    _Pragma("unroll") for (int mj = 0; mj < 2; ++mj)                           \
    _Pragma("unroll") for (int ks = 0; ks < 2; ++ks)                           \
      af[mj][ks] = RD_A(Aoff, 4 + mj, ks);                                     \
    if ((t) + 2 < NT) STAGE2(Wrow, 0, ((t) + 2) * 64, Boff + 0);               \
    CLUSTER(4);                                                                \
    /* p3: read A[6,7]; stage B1(t+2); c6; vmcnt(4|0); barrier */              \
    _Pragma("unroll") for (int mj = 0; mj < 2; ++mj)                           \
    _Pragma("unroll") for (int ks = 0; ks < 2; ++ks)                           \
      af[mj][ks] = RD_A(Aoff, 6 + mj, ks);                                     \
    if ((t) + 2 < NT) STAGE2(Wrow, 128, ((t) + 2) * 64, Boff + 8192);          \
    CLUSTER(6);                                                                \
    if ((t) + 2 < NT)                                                          \
      asm volatile("s_waitcnt vmcnt(4)" ::: "memory");                         \
    else                                                                       \
      asm volatile("s_waitcnt vmcnt(0)" ::: "memory");                         \
    __builtin_amdgcn_s_barrier();                                              \
  }

  // prologue: t0 {B0,B1,A0,A1} dbuf0; t1 {B0,B1} dbuf1 (A(t1) staged in t0's
  // p0/p1). vmcnt(4) drains B(t0)+A(t0); leaves {B(t1)}=4 = steady invariant.
  STAGE2(Wrow, 0, 0, 0);
  STAGE2(Wrow, 128, 0, 8192);
  STAGE2(Xrow, 0, 0, 16384);
  STAGE2(Xrow, 128, 0, 24576);
  STAGE2(Wrow, 0, 64, 32768);
  STAGE2(Wrow, 128, 64, 32768 + 8192);
  asm volatile("s_waitcnt vmcnt(4)" ::: "memory");
  __builtin_amdgcn_s_barrier();

  for (int tt = 0; tt < NT; tt += 2) {
    KTILE(0, tt);
    KTILE(1, tt + 1);
  }
#undef KTILE
#undef CLUSTER
#undef RD_A
#undef RD_B
#undef STAGE2

  // epilogue: C/D layout col=lane&15, row=(lane>>4)*4+i [m89/m91]
#pragma unroll
  for (int mi = 0; mi < 8; ++mi)
#pragma unroll
    for (int nf = 0; nf < 4; ++nf) {
      int row, col;
      if constexpr (TRANS) {
        row = n0 + wc * 64 + nf * 16 + fq * 4;
        col = m0 + wr * 128 + mi * 16 + fr;
      } else {
        row = m0 + wr * 128 + mi * 16 + fq * 4;
        col = n0 + wc * 64 + nf * 16 + fr;
      }
      if constexpr (OUT_F32) {
        float* yp = (float*)Yv + (size_t)row * kDM + col;
#pragma unroll
        for (int i = 0; i < 4; ++i) yp[(size_t)i * kDM] = acc[mi][nf][i];
      } else {
        u16* yp = (u16*)Yv + (size_t)row * kDM + col;
#pragma unroll
        for (int i = 0; i < 4; ++i) yp[(size_t)i * kDM] = f2bf(acc[mi][nf][i]);
      }
    }
}

// XCD-aware bijective remap (hw flat id -> work id; 8 XCDs, nwg%8==0)
static __device__ __forceinline__ int xcd_swz(int id, int cpx) {
  return (id & 7) * cpx + (id >> 3);
}

// Merged projections: z=0 Q, z=1 K (straight), z=2 V (transposed output).
__global__ __launch_bounds__(512, 2) void proj_all256_kernel(const u16* __restrict__ wsb,
                                                             u16* __restrict__ qp,
                                                             u16* __restrict__ kp,
                                                             u16* __restrict__ vpT) {
  __shared__ u16 lds[65536];
  const int z = blockIdx.z;
  const int s = xcd_swz(blockIdx.y * 16 + blockIdx.x, 32);
  const int m0 = (s >> 4) * 256, n0 = (s & 15) * 256;
  if (z == 0)
    gemm256<false, false>(wsb, wsb + 3 * kMat, qp, lds, m0, n0);
  else if (z == 1)
    gemm256<false, false>(wsb + kMat, wsb + 4 * kMat, kp, lds, m0, n0);
  else
    gemm256<true, false>(wsb + 2 * kMat, wsb + 5 * kMat, vpT, lds, m0, n0);
}

__global__ __launch_bounds__(512, 2) void out_proj256_kernel(const u16* __restrict__ ctx,
                                                             const u16* __restrict__ Wob,
                                                             float* __restrict__ out) {
  __shared__ u16 lds[65536];
  const int s = xcd_swz(blockIdx.y * 16 + blockIdx.x, 32);
  gemm256<false, true>(ctx, Wob, out, lds, (s >> 4) * 256, (s & 15) * 256);
}

// ---------------------------------------------------------------------------
// FALLBACK path (ws too small): in-GEMM convert staging (R5-verified).
// ---------------------------------------------------------------------------
template <bool A_BF16, bool TRANS, bool OUT_F32>
static __device__ __forceinline__ void gemm_conv(const void* Xv, const float* Wf,
                                                 void* Yv, u16* __restrict__ Als,
                                                 u16* __restrict__ Bls) {
  constexpr int KD = 4096;
  const int tid = threadIdx.x;
  const int lane = tid & 63;
  const int w = tid >> 6;
  const int fr = lane & 15;
  const int fq = lane >> 4;
  const int m0 = blockIdx.y * 128;
  const int n0 = blockIdx.x * 128;

  const int r0 = tid >> 2, cc0 = (tid & 3) * 8;
  const int r1 = r0 + 64;
  const int sr = lane >> 2, sc = (lane & 3) * 8;
  const int u0 = w * 2, u1 = w * 2 + 1;

  const u16* Xb = (const u16*)Xv;
  const float* Xf = (const float*)Xv;

  const int wm = (w >> 1) * 64;
  const int wn = (w & 1) * 64;

  f32x4 acc[4][4] = {};

  for (int kt = 0; kt < KD / 32; ++kt) {
    const int ko = kt * 32;
    if constexpr (A_BF16) {
      gload_lds16(Xb + (size_t)(m0 + u0 * 16 + sr) * KD + ko + sc, &Als[u0 * 512]);
      gload_lds16(Xb + (size_t)(m0 + u1 * 16 + sr) * KD + ko + sc, &Als[u1 * 512]);
    } else {
      const float* p0 = Xf + (size_t)(m0 + r0) * KD + ko + cc0;
      const float* p1 = Xf + (size_t)(m0 + r1) * KD + ko + cc0;
      float4 a0 = *(const float4*)(p0);
      float4 a1 = *(const float4*)(p0 + 4);
      float4 a2 = *(const float4*)(p1);
      float4 a3 = *(const float4*)(p1 + 4);
      *(u16x8*)&Als[r0 * 32 + cc0] = cvt8(a0, a1);
      *(u16x8*)&Als[r1 * 32 + cc0] = cvt8(a2, a3);
    }
    {
      const float* p0 = Wf + (size_t)(n0 + r0) * KD + ko + cc0;
      const float* p1 = Wf + (size_t)(n0 + r1) * KD + ko + cc0;
      float4 b0 = *(const float4*)(p0);
      float4 b1 = *(const float4*)(p0 + 4);
      float4 b2 = *(const float4*)(p1);
      float4 b3 = *(const float4*)(p1 + 4);
      *(u16x8*)&Bls[r0 * 32 + cc0] = cvt8(b0, b1);
      *(u16x8*)&Bls[r1 * 32 + cc0] = cvt8(b2, b3);
    }
    __syncthreads();

    bf16x8 af[4], bfv[4];
#pragma unroll
    for (int i = 0; i < 4; ++i)
      af[i] = *(const bf16x8*)&Als[(wm + i * 16 + fr) * 32 + fq * 8];
#pragma unroll
    for (int i = 0; i < 4; ++i)
      bfv[i] = *(const bf16x8*)&Bls[(wn + i * 16 + fr) * 32 + fq * 8];
#pragma unroll
    for (int a = 0; a < 4; ++a)
#pragma unroll
      for (int bb = 0; bb < 4; ++bb) {
        if constexpr (TRANS)
          acc[a][bb] = MFMA_BF16(bfv[a], af[bb], acc[a][bb]);
        else
          acc[a][bb] = MFMA_BF16(af[a], bfv[bb], acc[a][bb]);
      }
    __syncthreads();
  }

#pragma unroll
  for (int a = 0; a < 4; ++a)
#pragma unroll
    for (int bb = 0; bb < 4; ++bb) {
      const int row = TRANS ? (n0 + wn + a * 16 + fq * 4) : (m0 + wm + a * 16 + fq * 4);
      const int col = TRANS ? (m0 + wm + bb * 16 + fr) : (n0 + wn + bb * 16 + fr);
      if constexpr (OUT_F32) {
        float* yp = (float*)Yv + (size_t)row * kDM + col;
#pragma unroll
        for (int i = 0; i < 4; ++i) yp[(size_t)i * kDM] = acc[a][bb][i];
      } else {
        u16* yp = (u16*)Yv + (size_t)row * kDM + col;
#pragma unroll
        for (int i = 0; i < 4; ++i) yp[(size_t)i * kDM] = f2bf(acc[a][bb][i]);
      }
    }
}

__global__ __launch_bounds__(256) void proj_qk_conv_kernel(
    const float* __restrict__ q, const float* __restrict__ k,
    const float* __restrict__ Wq, const float* __restrict__ Wk,
    u16* __restrict__ qp, u16* __restrict__ kp) {
  __shared__ u16 Als[128 * 32];
  __shared__ u16 Bls[128 * 32];
  const int z = blockIdx.z;
  gemm_conv<false, false, false>(z ? k : q, z ? Wk : Wq, z ? kp : qp, Als, Bls);
}

__global__ __launch_bounds__(256) void proj_vT_conv_kernel(
    const float* __restrict__ v, const float* __restrict__ Wv, u16* __restrict__ vpT) {
  __shared__ u16 Als[128 * 32];
  __shared__ u16 Bls[128 * 32];
  gemm_conv<false, true, false>(v, Wv, vpT, Als, Bls);
}

__global__ __launch_bounds__(256) void out_proj_conv_kernel(const u16* __restrict__ ctx,
                                                            const float* __restrict__ Wo,
                                                            float* __restrict__ out) {
  __shared__ u16 Als[128 * 32];
  __shared__ u16 Bls[128 * 32];
  gemm_conv<true, false, true>(ctx, Wo, out, Als, Bls);
}

// ---------------------------------------------------------------------------
// Flash attention R18: as R9 but with consolidated setprio brackets (one
// around all of QK^T, one around PV+denom) — removes ~17 SALU toggle pairs
// per tile per wave and gives the scheduler coherent MFMA regions.
// ---------------------------------------------------------------------------
__global__ __launch_bounds__(512) void attn_kernel(const u16* __restrict__ qp,
                                                   const u16* __restrict__ kp,
                                                   const u16* __restrict__ vpT,
                                                   u16* __restrict__ ctx) {
  constexpr int KB = 64;
  constexpr int NT = kS / KB;   // 32 tiles
  constexpr int PST = 72;       // P row stride (elems, 16B-aligned rows)
  constexpr float THR = 11.5f;  // defer-max threshold (log2 units ~ e^8)

  __shared__ u16 Kls[KB * 128];        // 16 KB [key][d] chunk-swizzled
  __shared__ u16 Vt[kD * KB];          // 16 KB [d][key] chunk-swizzled
  __shared__ u16 Pls[8][2 * 16 * PST]; // 36 KB per-wave P tiles [q][key]

  const int tid = threadIdx.x, lane = tid & 63, w = tid >> 6;  // w: 0..7
  const int fr = lane & 15, fq = lane >> 4;

  const int wg = blockIdx.y * 8 + blockIdx.x;
  const int o = (wg & 7) * 64 + (wg >> 3);
  const int bh = o >> 3;
  const int b = bh >> 5, h = bh & 31;
  const int q0 = (o & 7) * 256;

  const u16* qbase = qp + ((size_t)b * kS) * kDM + h * kD;
  const u16* kbase = kp + ((size_t)b * kS) * kDM + h * kD;
  const u16* vtbase = vpT + (size_t)(h * kD) * kDM + b * kS;  // row d, stride kDM

  bf16x8 qf[2][4];
#pragma unroll
  for (int rb = 0; rb < 2; ++rb)
#pragma unroll
    for (int kc = 0; kc < 4; ++kc) {
      const u16x8 raw = *(const u16x8*)(qbase +
          (size_t)(q0 + w * 32 + rb * 16 + fr) * kDM + kc * 32 + fq * 8);
      bf16x8 s;
#pragma unroll
      for (int j = 0; j < 8; ++j) s[j] = (short)f2bf(bf2f(raw[j]) * kScaleLog2e);
      qf[rb][kc] = s;
    }

  f32x4 oacc[2][9] = {};
  float mrun[2] = {-1e30f, -1e30f};

  bf16x8 ones;
#pragma unroll
  for (int j = 0; j < 8; ++j) ones[j] = (short)0x3F80;  // bf16 1.0

  const int krl = lane >> 4, kdp = lane & 15;
  const int vdl = lane >> 3, vc = lane & 7;
  const int rk0 = (w * 2 + 0) * 4 + krl;
  const int rk1 = (w * 2 + 1) * 4 + krl;
  const int dv0 = (w * 2 + 0) * 8 + vdl;
  const int dv1 = (w * 2 + 1) * 8 + vdl;
  const u16* kg0 = kbase + (size_t)rk0 * kDM + kdp * 8;
  const u16* kg1 = kbase + (size_t)rk1 * kDM + kdp * 8;
  const u16* vg0 = vtbase + (size_t)dv0 * kDM + vc * 8;
  const u16* vg1 = vtbase + (size_t)dv1 * kDM + vc * 8;
  u16* kl0 = &Kls[rk0 * 128 + ((kdp ^ (rk0 & 7)) * 8)];
  u16* kl1 = &Kls[rk1 * 128 + ((kdp ^ (rk1 & 7)) * 8)];
  u16* vl0 = &Vt[dv0 * KB + ((vc ^ (dv0 & 7)) * 8)];
  u16* vl1 = &Vt[dv1 * KB + ((vc ^ (dv1 & 7)) * 8)];

  u16x8 kr0v, kr1v, vr0v, vr1v;
  kr0v = *(const u16x8*)kg0;
  kr1v = *(const u16x8*)kg1;
  vr0v = *(const u16x8*)vg0;
  vr1v = *(const u16x8*)vg1;
  *(u16x8*)kl0 = kr0v; *(u16x8*)kl1 = kr1v;
  *(u16x8*)vl0 = vr0v; *(u16x8*)vl1 = vr1v;
  __syncthreads();

  for (int kt = 0; kt < NT; ++kt) {
    if (kt + 1 < NT) {
      const size_t ko = (size_t)(kt + 1) * KB;
      kr0v = *(const u16x8*)(kg0 + ko * kDM);
      kr1v = *(const u16x8*)(kg1 + ko * kDM);
      vr0v = *(const u16x8*)(vg0 + ko);
      vr1v = *(const u16x8*)(vg1 + ko);
    }

    // --- QK^T (swapped: mfma(K, Q)); one setprio bracket ---
    f32x4 sacc[2][4] = {};
    {
      bf16x8 kf[4][4];
#pragma unroll
      for (int cb = 0; cb < 4; ++cb) {
        const int n = cb * 16 + fr;
#pragma unroll
        for (int kc = 0; kc < 4; ++kc) {
          const int d0 = kc * 4 + fq;
          kf[cb][kc] = *(const bf16x8*)&Kls[n * 128 + (d0 ^ (n & 7)) * 8];
        }
      }
      __builtin_amdgcn_s_setprio(1);
#pragma unroll
      for (int cb = 0; cb < 4; ++cb)
#pragma unroll
        for (int rb = 0; rb < 2; ++rb)
#pragma unroll
          for (int kc = 0; kc < 4; ++kc)
            sacc[rb][cb] = MFMA_BF16(kf[cb][kc], qf[rb][kc], sacc[rb][cb]);
      __builtin_amdgcn_s_setprio(0);
    }

    // --- online softmax: lane owns row q=fr; keys = cb*16 + fq*4 + i ---
#pragma unroll
    for (int rb = 0; rb < 2; ++rb) {
      float m = sacc[rb][0][0];
#pragma unroll
      for (int cb = 0; cb < 4; ++cb)
#pragma unroll
        for (int i = 0; i < 4; ++i) m = fmaxf(m, sacc[rb][cb][i]);
      m = fmaxf(m, __shfl_xor(m, 16));
      m = fmaxf(m, __shfl_xor(m, 32));

      if (__any(m - mrun[rb] > THR)) {
        const float mnew = fmaxf(mrun[rb], m);
        const float sclS = exp2f(mrun[rb] - mnew);
        mrun[rb] = mnew;
        float scl[4];
#pragma unroll
        for (int i = 0; i < 4; ++i) scl[i] = __shfl(sclS, fq * 4 + i);
#pragma unroll
        for (int db = 0; db < 9; ++db)
#pragma unroll
          for (int i = 0; i < 4; ++i) oacc[rb][db][i] *= scl[i];
      }

#pragma unroll
      for (int cb = 0; cb < 4; ++cb) {
        u16x4 pk;
#pragma unroll
        for (int i = 0; i < 4; ++i)
          pk[i] = nbf(exp2f(sacc[rb][cb][i] - mrun[rb]));
        *(u16x4*)&Pls[w][rb * (16 * PST) + fr * PST + cb * 16 + fq * 4] = pk;
      }
    }

    asm volatile("s_waitcnt lgkmcnt(0)" ::: "memory");

    // --- PV + denom (ones-V), one setprio bracket ---
    {
      bf16x8 pf[2][2];
#pragma unroll
      for (int rb = 0; rb < 2; ++rb)
#pragma unroll
        for (int kb = 0; kb < 2; ++kb)
          pf[rb][kb] = *(const bf16x8*)&Pls[w][rb * (16 * PST) + fr * PST + kb * 32 + fq * 8];
      __builtin_amdgcn_s_setprio(1);
#pragma unroll
      for (int db = 0; db < 8; ++db) {
        const int d = db * 16 + fr;
        bf16x8 vf0 = *(const bf16x8*)&Vt[d * KB + ((fq ^ (d & 7)) << 3)];
        bf16x8 vf1 = *(const bf16x8*)&Vt[d * KB + (((4 + fq) ^ (d & 7)) << 3)];
#pragma unroll
        for (int rb = 0; rb < 2; ++rb) {
          oacc[rb][db] = MFMA_BF16(pf[rb][0], vf0, oacc[rb][db]);
          oacc[rb][db] = MFMA_BF16(pf[rb][1], vf1, oacc[rb][db]);
        }
      }
#pragma unroll
      for (int rb = 0; rb < 2; ++rb) {
        oacc[rb][8] = MFMA_BF16(pf[rb][0], ones, oacc[rb][8]);
        oacc[rb][8] = MFMA_BF16(pf[rb][1], ones, oacc[rb][8]);
      }
      __builtin_amdgcn_s_setprio(0);
    }

    __syncthreads();
    if (kt + 1 < NT) {
      *(u16x8*)kl0 = kr0v; *(u16x8*)kl1 = kr1v;
      *(u16x8*)vl0 = vr0v; *(u16x8*)vl1 = vr1v;
    }
    __syncthreads();
  }

  u16* cbase = ctx + ((size_t)b * kS) * kDM + h * kD;
#pragma unroll
  for (int rb = 0; rb < 2; ++rb) {
    float inv[4];
#pragma unroll
    for (int i = 0; i < 4; ++i) inv[i] = 1.0f / oacc[rb][8][i];
#pragma unroll
    for (int db = 0; db < 8; ++db)
#pragma unroll
      for (int i = 0; i < 4; ++i) {
        const int row = q0 + w * 32 + rb * 16 + fq * 4 + i;
        const int col = db * 16 + fr;
        cbase[(size_t)row * kDM + col] = nbf(oacc[rb][db][i] * inv[i]);
      }
  }
}

// ---------------------------------------------------------------------------
extern "C" void kernel_launch(void* const* d_in, const int* in_sizes, int n_in,
                              void* d_out, int out_size, void* d_ws, size_t ws_size,
                              hipStream_t stream) {
  const float* q = (const float*)d_in[0];
  const float* k = (const float*)d_in[1];
  const float* v = (const float*)d_in[2];
  const float* Wq = (const float*)d_in[3];
  const float* Wk = (const float*)d_in[4];
  const float* Wv = (const float*)d_in[5];
  const float* Wo = (const float*)d_in[6];
  float* out = (float*)d_out;

  const size_t needFast = 11 * kMat * sizeof(u16);  // 7 bf16 inputs + qp/kp/vpT/ctx

  if (ws_size >= needFast) {
    u16* wsb = (u16*)d_ws;            // [0..6]: qb kb vb Wqb Wkb Wvb Wob
    u16* qp = wsb + 7 * kMat;
    u16* kp = wsb + 8 * kMat;
    u16* vpT = wsb + 9 * kMat;
    u16* ctx = wsb + 10 * kMat;

    cvt_kernel<<<dim3(1024, 7), 256, 0, stream>>>(q, k, v, Wq, Wk, Wv, Wo, wsb);
    proj_all256_kernel<<<dim3(16, 16, 3), 512, 0, stream>>>(wsb, qp, kp, vpT);
    attn_kernel<<<dim3(8, 64), 512, 0, stream>>>(qp, kp, vpT, ctx);
    out_proj256_kernel<<<dim3(16, 16), 512, 0, stream>>>(ctx, wsb + 6 * kMat, out);
  } else {
    u16* qp = (u16*)d_ws;
    u16* kp = qp + kMat;
    u16* vpT = kp + kMat;
    u16* ctx = vpT + kMat;

    proj_qk_conv_kernel<<<dim3(32, 32, 2), 256, 0, stream>>>(q, k, Wq, Wk, qp, kp);
    proj_vT_conv_kernel<<<dim3(32, 32), 256, 0, stream>>>(v, Wv, vpT);
    attn_kernel<<<dim3(8, 64), 512, 0, stream>>>(qp, kp, vpT, ctx);
    out_proj_conv_kernel<<<dim3(32, 32, 1), 256, 0, stream>>>(ctx, Wo, out);
  }
}